// Round 16
// baseline (6005.399 us; speedup 1.0000x reference)
//
#include <hip/hip_runtime.h>
#include <hip/hip_bf16.h>
#include <math.h>

// ---------------- model dims ----------------
constexpr long TOK  = 32768;            // B*N*T
constexpr long HALF = TOK * 768;
constexpr int FLAG_ACC = 1, FLAG_GELU = 2, FLAG_PERM = 4, FLAG_BF16 = 8;

typedef __bf16 bf16x8 __attribute__((ext_vector_type(8)));
typedef __bf16 bf16x4 __attribute__((ext_vector_type(4)));
typedef float  f32x4  __attribute__((ext_vector_type(4)));

__device__ __forceinline__ void gload_lds16(const void* g, void* l) {
    __builtin_amdgcn_global_load_lds(
        (const __attribute__((address_space(1))) void*)g,
        (__attribute__((address_space(3))) void*)l, 16, 0, 0);
}
__device__ __forceinline__ float bf2f(__hip_bfloat16 v) { return __bfloat162float(v); }

// ======== 256x256 GEMM, 2 phases/K-tile (32 MFMA/phase), counted vmcnt ========
__global__ __launch_bounds__(512, 2) void gemm256(
    const __hip_bfloat16* __restrict__ A,
    const __hip_bfloat16* __restrict__ BT,
    const float* __restrict__ bias,
    void* __restrict__ Cv, int ldc,
    int M, int N, int K, int flags, int moff)
{
    __shared__ __align__(16) __hip_bfloat16 As[2][256 * 64];   // 64 KB
    __shared__ __align__(16) __hip_bfloat16 Bs[2][256 * 64];   // 64 KB
    const int tid = threadIdx.x;
    const int wid = tid >> 6, lane = tid & 63;
    const int wm = wid >> 2, wn = wid & 3;       // 2 x 4 wave grid
    const int lrow = lane & 15, lk = lane >> 4;
    // bijective XCD swizzle (m204)
    const int nwg = gridDim.x * gridDim.y;
    const int orig = blockIdx.y * gridDim.x + blockIdx.x;
    const int q8 = nwg >> 3, r8 = nwg & 7;
    const int xcd = orig & 7, off = orig >> 3;
    const int wgid = (xcd < r8 ? xcd * (q8 + 1) : r8 * (q8 + 1) + (xcd - r8) * q8) + off;
    const int bm = (wgid / gridDim.x) * 256, bn = (wgid % gridDim.x) * 256;
    const int nk = K >> 6;

    f32x4 acc[4][8];   // [nf][mf]; lane: row=lrow, 4 consecutive cols (lk*4)
#pragma unroll
    for (int nf = 0; nf < 4; nf++)
#pragma unroll
        for (int mf = 0; mf < 8; mf++) acc[nf][mf] = f32x4{0.f, 0.f, 0.f, 0.f};

    bf16x8 Af[4][2];   // current m-half quad frags x ks
    bf16x8 B0[2][2];   // n-frags 0-1 x ks (live whole K-tile)
    bf16x8 B1[2][2];   // n-frags 2-3 x ks (live whole K-tile)

    auto stage = [&](int kt, int which) {   // which: 0=A0,1=A1,2=B0,3=B1
        if (kt >= nk) return;
        const int dbuf = kt & 1;
        __hip_bfloat16* lbase = (which >= 2 ? &Bs[dbuf][0] : &As[dbuf][0]) + (which & 1) * 8192;
        const __hip_bfloat16* g = (which >= 2 ? BT : A);
        const int trow = (which >= 2 ? bn : bm) + (which & 1) * 128;
#pragma unroll
        for (int i = 0; i < 2; i++) {
            const int slot = i * 512 + tid;          // 0..1023 (16B units)
            const int rl = slot >> 3, ch = slot & 7;
            const int sc = (ch ^ (rl & 7)) * 8;      // inverse-swizzled source col
            const long src = (long)(trow + rl) * K + (long)kt * 64 + sc;
            char* l = (char*)lbase + (i * 512 + wid * 64) * 16;   // wave-uniform base
            gload_lds16(g + src, l);
        }
    };
    auto readA = [&](int dbuf, int mh) {
#pragma unroll
        for (int mq = 0; mq < 4; mq++)
#pragma unroll
            for (int ks = 0; ks < 2; ks++) {
                const int r = wm * 128 + mh * 64 + mq * 16 + lrow;
                const int ch = ((ks * 4 + lk) ^ (r & 7)) * 8;
                Af[mq][ks] = *(const bf16x8*)(const void*)&As[dbuf][r * 64 + ch];
            }
    };
    auto readB0 = [&](int dbuf) {
#pragma unroll
        for (int nf = 0; nf < 2; nf++)
#pragma unroll
            for (int ks = 0; ks < 2; ks++) {
                const int r = wn * 64 + nf * 16 + lrow;
                const int ch = ((ks * 4 + lk) ^ (r & 7)) * 8;
                B0[nf][ks] = *(const bf16x8*)(const void*)&Bs[dbuf][r * 64 + ch];
            }
    };
    auto readB1 = [&](int dbuf) {
#pragma unroll
        for (int nf = 0; nf < 2; nf++)
#pragma unroll
            for (int ks = 0; ks < 2; ks++) {
                const int r = wn * 64 + (2 + nf) * 16 + lrow;
                const int ch = ((ks * 4 + lk) ^ (r & 7)) * 8;
                B1[nf][ks] = *(const bf16x8*)(const void*)&Bs[dbuf][r * 64 + ch];
            }
    };

    // ---- prologue: K-tile 0 complete + B-halves of K-tile 1; leave 4 in flight ----
    stage(0, 0); stage(0, 1); stage(0, 2); stage(0, 3);
    stage(1, 2); stage(1, 3);
    asm volatile("s_waitcnt vmcnt(4)" ::: "memory");
    __builtin_amdgcn_s_barrier();

    for (int kt = 0; kt < nk; kt++) {
        const int cur = kt & 1;
        // ---- Phase A: mh0 x all nf (32 MFMA); stage A-halves of kt+1 -> other dbuf ----
        readA(cur, 0); readB0(cur); readB1(cur);
        stage(kt + 1, 0); stage(kt + 1, 1);
        __builtin_amdgcn_s_barrier();
        __builtin_amdgcn_s_setprio(1);
#pragma unroll
        for (int ks = 0; ks < 2; ks++) {
#pragma unroll
            for (int nf = 0; nf < 2; nf++)
#pragma unroll
                for (int mq = 0; mq < 4; mq++)
                    acc[nf][mq] = __builtin_amdgcn_mfma_f32_16x16x32_bf16(B0[nf][ks], Af[mq][ks], acc[nf][mq], 0, 0, 0);
#pragma unroll
            for (int nf = 0; nf < 2; nf++)
#pragma unroll
                for (int mq = 0; mq < 4; mq++)
                    acc[2 + nf][mq] = __builtin_amdgcn_mfma_f32_16x16x32_bf16(B1[nf][ks], Af[mq][ks], acc[2 + nf][mq], 0, 0, 0);
        }
        __builtin_amdgcn_s_setprio(0);
        __builtin_amdgcn_s_barrier();
        // ---- Phase B: mh1 x all nf; stage B-halves of kt+2 -> cur dbuf (B consumed) ----
        readA(cur, 1);
        stage(kt + 2, 2); stage(kt + 2, 3);
        if (kt + 2 < nk) asm volatile("s_waitcnt vmcnt(4)" ::: "memory");
        else             asm volatile("s_waitcnt vmcnt(0)" ::: "memory");
        __builtin_amdgcn_s_barrier();
        __builtin_amdgcn_s_setprio(1);
#pragma unroll
        for (int ks = 0; ks < 2; ks++) {
#pragma unroll
            for (int nf = 0; nf < 2; nf++)
#pragma unroll
                for (int mq = 0; mq < 4; mq++)
                    acc[nf][4 + mq] = __builtin_amdgcn_mfma_f32_16x16x32_bf16(B0[nf][ks], Af[mq][ks], acc[nf][4 + mq], 0, 0, 0);
#pragma unroll
            for (int nf = 0; nf < 2; nf++)
#pragma unroll
                for (int mq = 0; mq < 4; mq++)
                    acc[2 + nf][4 + mq] = __builtin_amdgcn_mfma_f32_16x16x32_bf16(B1[nf][ks], Af[mq][ks], acc[2 + nf][4 + mq], 0, 0, 0);
        }
        __builtin_amdgcn_s_setprio(0);
        __builtin_amdgcn_s_barrier();
    }

    float* Cf = (float*)Cv;
    __hip_bfloat16* Cb = (__hip_bfloat16*)Cv;
    if (flags & FLAG_BF16) {
        // coalesced bf16 store via per-wave-private LDS (stride 176B: 2-way max aliasing)
        char* lw = (char*)&As[0][0] + (size_t)wid * (64 * 176);   // 11 KB/wave
        const int colg = bn + wn * 64;
#pragma unroll
        for (int half = 0; half < 2; half++) {
#pragma unroll
            for (int nf = 0; nf < 4; nf++) {
                const int col = nf * 16 + lk * 4;
                f32x4 b4 = f32x4{0.f, 0.f, 0.f, 0.f};
                if (bias) b4 = *(const f32x4*)&bias[colg + col];
#pragma unroll
                for (int m4 = 0; m4 < 4; m4++) {
                    const int row = m4 * 16 + lrow;
                    f32x4 v = acc[nf][half * 4 + m4] + b4;
                    if (flags & FLAG_GELU) {
#pragma unroll
                        for (int j = 0; j < 4; j++) {
                            const float x = v[j];
                            const float u = 1.5957691216057308f * (x + 0.044715f * x * x * x);
                            v[j] = x / (1.f + __expf(-u));
                        }
                    }
                    if (flags & FLAG_ACC) {   // bf16 read-modify-write residual
                        const long gr = (long)(bm + wm * 128 + half * 64 + row);
                        const bf16x4 old = *(const bf16x4*)(const void*)&Cb[gr * ldc + colg + col];
#pragma unroll
                        for (int j = 0; j < 4; j++) v[j] += (float)old[j];
                    }
                    bf16x4 o;
                    o[0] = (__bf16)v[0]; o[1] = (__bf16)v[1];
                    o[2] = (__bf16)v[2]; o[3] = (__bf16)v[3];
                    *(bf16x4*)(void*)(lw + row * 176 + col * 2) = o;
                }
            }
            asm volatile("s_waitcnt lgkmcnt(0)" ::: "memory");
#pragma unroll
            for (int rr = 0; rr < 8; rr++) {
                const int row = rr * 8 + (lane >> 3);
                const long gr = (long)(bm + wm * 128 + half * 64 + row);
                const bf16x8 d = *(const bf16x8*)(const void*)(lw + row * 176 + (lane & 7) * 16);
                *(bf16x8*)(void*)&Cb[gr * ldc + colg + (lane & 7) * 8] = d;
            }
            asm volatile("s_waitcnt lgkmcnt(0)" ::: "memory");
        }
    } else {
#pragma unroll
        for (int nf = 0; nf < 4; nf++) {
            const int gcb = bn + wn * 64 + nf * 16 + lk * 4;
            if (gcb >= N) continue;
            f32x4 b4 = f32x4{0.f, 0.f, 0.f, 0.f};
            if (bias) b4 = *(const f32x4*)&bias[gcb];
#pragma unroll
            for (int mf = 0; mf < 8; mf++) {
                const int gr = bm + wm * 128 + mf * 16 + lrow;
                f32x4 v = acc[nf][mf] + b4;
                if (flags & FLAG_GELU) {
#pragma unroll
                    for (int j = 0; j < 4; j++) {
                        const float x = v[j];
                        const float u = 1.5957691216057308f * (x + 0.044715f * x * x * x);
                        v[j] = x / (1.f + __expf(-u));
                    }
                }
                if (flags & FLAG_PERM) {
                    const int mg = moff + gr;
                    const int b_ = mg >> 13, t_ = (mg >> 7) & 63, n_ = mg & 127;
                    *(f32x4*)&Cf[(((long)(b_ * 128 + n_)) * 64 + t_) * ldc + gcb] = v;
                } else if (flags & FLAG_ACC) {
                    float* dst = &Cf[(long)gr * ldc + gcb];
                    f32x4 old = *(const f32x4*)dst;
                    *(f32x4*)dst = old + v;
                } else {
                    *(f32x4*)&Cf[(long)gr * ldc + gcb] = v;
                }
            }
        }
    }
}

// ---------------- bf16 MFMA GEMM: 128x128 (small-grid / non-256 shapes) ----------
__global__ __launch_bounds__(256) void gemm_bf16(
    const __hip_bfloat16* __restrict__ A,
    const __hip_bfloat16* __restrict__ BT,
    const float* __restrict__ bias,
    void* __restrict__ Cv, int ldc,
    int M, int N, int K, int flags, int moff)
{
    __shared__ __hip_bfloat16 As[2][128 * 32];
    __shared__ __hip_bfloat16 Bs[2][128 * 32];
    const int tid = threadIdx.x;
    const int wv = tid >> 6, lane = tid & 63;
    const int nwg = gridDim.x * gridDim.y;
    const int orig = blockIdx.y * gridDim.x + blockIdx.x;
    const int q8 = nwg >> 3, r8 = nwg & 7;
    const int xcd = orig & 7, off = orig >> 3;
    const int wgid = (xcd < r8 ? xcd * (q8 + 1) : r8 * (q8 + 1) + (xcd - r8) * q8) + off;
    const int bm = (wgid / gridDim.x) * 128, bn = (wgid % gridDim.x) * 128;
    const int wr = (wv >> 1) * 64, wc = (wv & 1) * 64;
    const int lrow = lane & 15, lk = lane >> 4;
    const int ck = (lk ^ (lrow & 3) ^ ((lrow >> 2) & 3)) * 8;

    f32x4 acc[4][4];
#pragma unroll
    for (int n = 0; n < 4; n++)
#pragma unroll
        for (int m = 0; m < 4; m++) acc[n][m] = f32x4{0.f, 0.f, 0.f, 0.f};

    const int nk = K >> 5;
    auto stage = [&](int kt, int buf) {
#pragma unroll
        for (int i = 0; i < 2; i++) {
            const int lin = i * 256 + tid;
            const int row = lin >> 2;
            const int ks  = (((lin & 3) ^ (row & 3) ^ ((row >> 2) & 3)) * 8);
            const long asrc = (long)(bm + row) * K + kt * 32 + ks;
            const long bsrc = (long)(bn + row) * K + kt * 32 + ks;
            char* la = (char*)&As[buf][0] + (i * 256 + wv * 64) * 16;
            char* lb = (char*)&Bs[buf][0] + (i * 256 + wv * 64) * 16;
            gload_lds16(A + asrc, la);
            gload_lds16(BT + bsrc, lb);
        }
    };

    stage(0, 0);
    __syncthreads();
    for (int kt = 0; kt < nk; kt++) {
        const int cur = kt & 1;
        if (kt + 1 < nk) stage(kt + 1, cur ^ 1);
        bf16x8 af[4], bfr[4];
#pragma unroll
        for (int m = 0; m < 4; m++) {
            af[m]  = *(const bf16x8*)(const void*)&As[cur][(wr + m * 16 + lrow) * 32 + ck];
            bfr[m] = *(const bf16x8*)(const void*)&Bs[cur][(wc + m * 16 + lrow) * 32 + ck];
        }
#pragma unroll
        for (int n = 0; n < 4; n++)
#pragma unroll
            for (int m = 0; m < 4; m++)
                acc[n][m] = __builtin_amdgcn_mfma_f32_16x16x32_bf16(bfr[n], af[m], acc[n][m], 0, 0, 0);
        __syncthreads();
    }

    float* Cf = (float*)Cv;
    __hip_bfloat16* Cb = (__hip_bfloat16*)Cv;
#pragma unroll
    for (int n = 0; n < 4; n++) {
        const int gcb = bn + wc + n * 16 + lk * 4;
        if (gcb >= N) continue;
        f32x4 b4 = f32x4{0.f, 0.f, 0.f, 0.f};
        if (bias) b4 = *(const f32x4*)&bias[gcb];
#pragma unroll
        for (int m = 0; m < 4; m++) {
            const int gr = bm + wr + m * 16 + lrow;
            f32x4 v = acc[n][m] + b4;
            if (flags & FLAG_GELU) {
#pragma unroll
                for (int j = 0; j < 4; j++) {
                    const float x = v[j];
                    const float u = 1.5957691216057308f * (x + 0.044715f * x * x * x);
                    v[j] = x / (1.f + __expf(-u));
                }
            }
            if (flags & FLAG_PERM) {
                const int mg = moff + gr;
                const int b_ = mg >> 13, t_ = (mg >> 7) & 63, n_ = mg & 127;
                *(f32x4*)&Cf[(((long)(b_ * 128 + n_)) * 64 + t_) * ldc + gcb] = v;
            } else if (flags & FLAG_BF16) {
                if (flags & FLAG_ACC) {
                    const bf16x4 old = *(const bf16x4*)(const void*)&Cb[(long)gr * ldc + gcb];
#pragma unroll
                    for (int j = 0; j < 4; j++) v[j] += (float)old[j];
                }
                __hip_bfloat16 o0 = __float2bfloat16(v[0]), o1 = __float2bfloat16(v[1]);
                __hip_bfloat16 o2 = __float2bfloat16(v[2]), o3 = __float2bfloat16(v[3]);
                ushort4 o = { *(ushort*)&o0, *(ushort*)&o1, *(ushort*)&o2, *(ushort*)&o3 };
                *(ushort4*)&Cb[(long)gr * ldc + gcb] = o;
            } else if (flags & FLAG_ACC) {
                float* dst = &Cf[(long)gr * ldc + gcb];
                f32x4 old = *(const f32x4*)dst;
                *(f32x4*)dst = old + v;
            } else {
                *(f32x4*)&Cf[(long)gr * ldc + gcb] = v;
            }
        }
    }
}

// ---------------- weight transpose-convert: W (KxN f32) -> WT (Npad x K bf16) ----
__global__ void convT_kernel(const float* __restrict__ W, __hip_bfloat16* __restrict__ WT,
                             int K, int N, int Npad)
{
    __shared__ float t[32][33];
    const int k0 = blockIdx.y * 32, n0 = blockIdx.x * 32;
    const int tx = threadIdx.x & 31, ty = threadIdx.x >> 5;
#pragma unroll
    for (int i = 0; i < 4; i++) {
        int k = k0 + ty + i * 8, n = n0 + tx;
        t[ty + i * 8][tx] = (k < K && n < N) ? W[(long)k * N + n] : 0.f;
    }
    __syncthreads();
#pragma unroll
    for (int i = 0; i < 4; i++) {
        int n = n0 + ty + i * 8, k = k0 + tx;
        if (n < Npad && k < K) WT[(long)n * K + k] = __float2bfloat16(t[tx][ty + i * 8]);
    }
}

// ---------------- f32 -> bf16 elementwise ----------------
__global__ void cvt_kernel(const float4* __restrict__ x, ushort4* __restrict__ y, long n4)
{
    long i = (long)blockIdx.x * 256 + threadIdx.x;
    if (i >= n4) return;
    float4 v = x[i];
    __hip_bfloat16 a = __float2bfloat16(v.x), b = __float2bfloat16(v.y);
    __hip_bfloat16 c = __float2bfloat16(v.z), d = __float2bfloat16(v.w);
    ushort4 o = { *(ushort*)&a, *(ushort*)&b, *(ushort*)&c, *(ushort*)&d };
    y[i] = o;
}

// ---------------- RMSNorm, wave-per-row, vectorized bf16 input ----------------
__global__ void rmsnorm_b16(const __hip_bfloat16* __restrict__ x, const float* __restrict__ w,
                            __hip_bfloat16* __restrict__ out, int D, int xs, int os, long nrows)
{
    const int wv = threadIdx.x >> 6, lane = threadIdx.x & 63;
    const long row = (long)blockIdx.x * 4 + wv;
    if (row >= nrows) return;
    const __hip_bfloat16* xr = x + row * xs;
    const int it = D >> 8;
    float ss = 0.f;
    for (int i = 0; i < it; i++) {
        const bf16x4 v = *(const bf16x4*)(const void*)&xr[(i * 64 + lane) * 4];
#pragma unroll
        for (int e = 0; e < 4; e++) { const float f = (float)v[e]; ss += f * f; }
    }
    for (int o = 32; o; o >>= 1) ss += __shfl_xor(ss, o);
    const float sc = rsqrtf(ss / D + 1e-5f);
    __hip_bfloat16* orow = out + row * os;
    for (int i = 0; i < it; i++) {
        const int e = (i * 64 + lane) * 4;
        const bf16x4 v = *(const bf16x4*)(const void*)&xr[e];
        const float4 g = *(const float4*)&w[e];
        bf16x4 o;
        o[0] = (__bf16)((float)v[0] * sc * g.x); o[1] = (__bf16)((float)v[1] * sc * g.y);
        o[2] = (__bf16)((float)v[2] * sc * g.z); o[3] = (__bf16)((float)v[3] * sc * g.w);
        *(bf16x4*)(void*)&orow[e] = o;
    }
}

// ---------------- fused attention, MFMA version: block per (batch, head) --------
__global__ __launch_bounds__(256) void attn_kernel(
    const __hip_bfloat16* __restrict__ QKV, __hip_bfloat16* __restrict__ O)
{
    __shared__ __align__(16) __hip_bfloat16 Qs[3 * 64 * 32];
    __shared__ __align__(16) __hip_bfloat16 Ks[3 * 64 * 32];
    __shared__ __align__(16) __hip_bfloat16 VT[2 * 96 * 32];
    __shared__ __align__(16) __hip_bfloat16 Ps[2 * 64 * 32];
    const int tid = threadIdx.x;
    const int wid = tid >> 6, lane = tid & 63;
    const int lrow = lane & 15, lk = lane >> 4;
    const int b = blockIdx.x >> 3, h = blockIdx.x & 7;
    const long base = (long)b * 64 * 2304 + h * 96;

#pragma unroll
    for (int i = 0; i < 3; i++) {
        const int v = i * 256 + tid;
        const int r = v / 12, c8 = v - r * 12;
        const int kst = c8 >> 2, ch = c8 & 3, slot = ch ^ (r & 3);
        const bf16x8 q = *(const bf16x8*)(const void*)&QKV[base + (long)r * 2304 + c8 * 8];
        const bf16x8 k = *(const bf16x8*)(const void*)&QKV[base + (long)r * 2304 + 768 + c8 * 8];
        *(bf16x8*)(void*)&Qs[(kst * 64 + r) * 32 + slot * 8] = q;
        *(bf16x8*)(void*)&Ks[(kst * 64 + r) * 32 + slot * 8] = k;
    }
    for (int i = 0; i < 16; i++) {
        const int k = wid * 16 + i;
        const __hip_bfloat16* vrow = &QKV[base + (long)k * 2304 + 1536];
        const int sb = (k >> 3) & 3, khi = k >> 5, klo = k & 7;
        {
            const int d = lane;
            VT[(khi * 96 + d) * 32 + ((sb ^ (d & 3)) * 8) + klo] = vrow[d];
        }
        if (lane < 32) {
            const int d = 64 + lane;
            VT[(khi * 96 + d) * 32 + ((sb ^ (d & 3)) * 8) + klo] = vrow[d];
        }
    }
    __syncthreads();

    const int ck = (lk ^ (lrow & 3)) * 8;
    f32x4 s[4];
#pragma unroll
    for (int n = 0; n < 4; n++) s[n] = f32x4{0.f, 0.f, 0.f, 0.f};
#pragma unroll
    for (int kst = 0; kst < 3; kst++) {
        const bf16x8 qf = *(const bf16x8*)(const void*)&Qs[(kst * 64 + wid * 16 + lrow) * 32 + ck];
#pragma unroll
        for (int n = 0; n < 4; n++) {
            const bf16x8 kf = *(const bf16x8*)(const void*)&Ks[(kst * 64 + n * 16 + lrow) * 32 + ck];
            s[n] = __builtin_amdgcn_mfma_f32_16x16x32_bf16(qf, kf, s[n], 0, 0, 0);
        }
    }
    const float scale = 0.102062072615966f;
#pragma unroll
    for (int n = 0; n < 4; n++) s[n] *= scale;
    float inv[4];
#pragma unroll
    for (int j = 0; j < 4; j++) {
        float mx = fmaxf(fmaxf(s[0][j], s[1][j]), fmaxf(s[2][j], s[3][j]));
        mx = fmaxf(mx, __shfl_xor(mx, 1));
        mx = fmaxf(mx, __shfl_xor(mx, 2));
        mx = fmaxf(mx, __shfl_xor(mx, 4));
        mx = fmaxf(mx, __shfl_xor(mx, 8));
        float sum = 0.f;
#pragma unroll
        for (int n = 0; n < 4; n++) { s[n][j] = __expf(s[n][j] - mx); sum += s[n][j]; }
        sum += __shfl_xor(sum, 1);
        sum += __shfl_xor(sum, 2);
        sum += __shfl_xor(sum, 4);
        sum += __shfl_xor(sum, 8);
        inv[j] = 1.f / sum;
    }
#pragma unroll
    for (int n = 0; n < 4; n++) {
        const int k = n * 16 + lrow;
        const int kst = n >> 1, kc = ((n & 1) << 1) + (lrow >> 3), ke = lrow & 7;
#pragma unroll
        for (int j = 0; j < 4; j++) {
            const int q = wid * 16 + lk * 4 + j;
            Ps[(kst * 64 + q) * 32 + ((kc ^ (q & 3)) * 8) + ke] = __float2bfloat16(s[n][j] * inv[j]);
        }
    }
    __syncthreads();

    const int wq = wid >> 1, wd = wid & 1;
    f32x4 y[3][2];
#pragma unroll
    for (int mv = 0; mv < 3; mv++)
#pragma unroll
        for (int np = 0; np < 2; np++) y[mv][np] = f32x4{0.f, 0.f, 0.f, 0.f};
#pragma unroll
    for (int ks = 0; ks < 2; ks++) {
        bf16x8 vf[3], pf[2];
#pragma unroll
        for (int mv = 0; mv < 3; mv++)
            vf[mv] = *(const bf16x8*)(const void*)&VT[(ks * 96 + wd * 48 + mv * 16 + lrow) * 32 + ck];
#pragma unroll
        for (int np = 0; np < 2; np++)
            pf[np] = *(const bf16x8*)(const void*)&Ps[(ks * 64 + wq * 32 + np * 16 + lrow) * 32 + ck];
#pragma unroll
        for (int mv = 0; mv < 3; mv++)
#pragma unroll
            for (int np = 0; np < 2; np++)
                y[mv][np] = __builtin_amdgcn_mfma_f32_16x16x32_bf16(vf[mv], pf[np], y[mv][np], 0, 0, 0);
    }
#pragma unroll
    for (int mv = 0; mv < 3; mv++) {
        const int d0 = wd * 48 + mv * 16 + lk * 4;
#pragma unroll
        for (int np = 0; np < 2; np++) {
            const int q = wq * 32 + np * 16 + lrow;
            bf16x4 o;
#pragma unroll
            for (int j = 0; j < 4; j++) o[j] = (__bf16)y[mv][np][j];
            *(bf16x4*)(void*)&O[(long)(b * 64 + q) * 768 + h * 96 + d0] = o;
        }
    }
}

// ------------ transpose p (B,N,T,D) -> z (B,T,N,D), bf16, 4 elems/thread --------
__global__ void transpose_kernel(const __hip_bfloat16* __restrict__ P, __hip_bfloat16* __restrict__ Z)
{
    long lin4 = (long)blockIdx.x * 256 + threadIdx.x;
    if (lin4 >= HALF / 4) return;
    int d4 = (int)(lin4 % 192);
    long rowz = lin4 / 192;
    int n = rowz & 127, t = (int)((rowz >> 7) & 63), b = (int)(rowz >> 13);
    long rowp = ((long)(b * 128 + n)) * 64 + t;
    const bf16x4 v = *(const bf16x4*)(const void*)&P[rowp * 768 + d4 * 4];
    *(bf16x4*)(void*)&Z[rowz * 768 + d4 * 4] = v;
}

// -------- causal depthwise conv + SiLU, vectorized: block per row, 8 chan/thread
__global__ __launch_bounds__(256) void conv_kernel(
    const __hip_bfloat16* __restrict__ zx, const float* __restrict__ cw,
    const float* __restrict__ cb, __hip_bfloat16* __restrict__ xc,
    __hip_bfloat16* __restrict__ bcB, long rows)
{
    const long r = blockIdx.x;
    const int tid = threadIdx.x;
    if (tid >= 208) return;
    const int c0 = tid * 8;
    const int n = (int)(r & 127);
    float acc[8];
    {
        const float4 b0 = *(const float4*)&cb[c0];
        const float4 b1 = *(const float4*)&cb[c0 + 4];
        acc[0] = b0.x; acc[1] = b0.y; acc[2] = b0.z; acc[3] = b0.w;
        acc[4] = b1.x; acc[5] = b1.y; acc[6] = b1.z; acc[7] = b1.w;
    }
#pragma unroll
    for (int k = 0; k < 4; k++) {
        if (n - 3 + k < 0) continue;
        const bf16x8 xv = *(const bf16x8*)(const void*)&zx[(r - 3 + k) * 3328 + 1536 + c0];
        const float4 w0 = *(const float4*)&cw[k * 1664 + c0];
        const float4 w1 = *(const float4*)&cw[k * 1664 + c0 + 4];
        acc[0] += w0.x * (float)xv[0]; acc[1] += w0.y * (float)xv[1];
        acc[2] += w0.z * (float)xv[2]; acc[3] += w0.w * (float)xv[3];
        acc[4] += w1.x * (float)xv[4]; acc[5] += w1.y * (float)xv[5];
        acc[6] += w1.z * (float)xv[6]; acc[7] += w1.w * (float)xv[7];
    }
    bf16x8 o;
#pragma unroll
    for (int e = 0; e < 8; e++) {
        const float s = acc[e] / (1.f + __expf(-acc[e]));
        o[e] = (__bf16)s;
    }
    if (c0 < 1536) *(bf16x8*)(void*)&xc[r * 1664 + c0] = o;
    else           *(bf16x8*)(void*)&bcB[r * 128 + (c0 - 1536)] = o;
}

// ---------------- dt = softplus(dt_raw + bias) -> f32 side buffer ----------------
__global__ void dt_kernel(const __hip_bfloat16* __restrict__ zx, const float* __restrict__ bias,
                          float* __restrict__ dtf, long count)
{
    long lin = (long)blockIdx.x * 256 + threadIdx.x;
    if (lin >= count) return;
    int h = (int)(lin % 24);
    long r = lin / 24;
    float v = bf2f(zx[r * 3328 + 3200 + h]) + bias[h];
    dtf[lin] = (v > 0.f) ? v + log1pf(expf(-v)) : log1pf(expf(v));
}

// ======== SSD kernel v2: wave-0 shfl scan, swapped-operand GEMMs, __expf ========
__global__ __launch_bounds__(256) void ssd_kernel(
    const __hip_bfloat16* __restrict__ zx0, const float* __restrict__ dtf0,
    const __hip_bfloat16* __restrict__ bcB0, __hip_bfloat16* __restrict__ xc0,
    const float* __restrict__ Alog, const float* __restrict__ Dskip,
    float* __restrict__ hout, int bt0)
{
    __shared__ __align__(16) char SM[50688];
    __hip_bfloat16* Cl  = (__hip_bfloat16*)SM;            // [2][128][32]
    __hip_bfloat16* Bl  = Cl + 8192;                      // [2][128][32]
    __hip_bfloat16* Ml  = (__hip_bfloat16*)SM;            // [4][128][32] overlays Cl+Bl
    __hip_bfloat16* XTl = (__hip_bfloat16*)(SM + 32768);  // [4][64][32]  (X^T: [p][t])
    __hip_bfloat16* BTl = (__hip_bfloat16*)SM;            // [4][64][32]  overlays Ml (hT)
    float* cum = (float*)(SM + 49152);                    // [128]
    float* dtl = cum + 128;                               // [128]
    float* wl  = dtl + 128;                               // [128]

    const int tid = threadIdx.x;
    const int wid = tid >> 6, lane = tid & 63;
    const int lrow = lane & 15, lk = lane >> 4;
    const int btl = blockIdx.x / 24, h = blockIdx.x % 24;
    const long rowbase = (long)btl * 128;

    const __hip_bfloat16* zxp = zx0 + rowbase * 3328 + h * 64;
    const float* dtp = dtf0 + rowbase * 24;
    const __hip_bfloat16* bcp = bcB0 + rowbase * 128;
    __hip_bfloat16* xcp = xc0 + rowbase * 1664 + h * 64;

    const float A  = -__expf(Alog[h]);
    const float Dh = Dskip[h];

#pragma unroll
    for (int i = 0; i < 4; i++) {
        const int v = tid + i * 256;
        const int row = v >> 3, c8 = v & 7;
        const int kst = c8 >> 2, ch = c8 & 3;
        const int slot = ch ^ (row & 3);
        bf16x8 vB = *(const bf16x8*)(const void*)&bcp[(long)row * 128 + c8 * 8];
        bf16x8 vC = *(const bf16x8*)(const void*)&bcp[(long)row * 128 + 64 + c8 * 8];
        *(bf16x8*)(void*)&Bl[(kst * 128 + row) * 32 + slot * 8] = vB;
        *(bf16x8*)(void*)&Cl[(kst * 128 + row) * 32 + slot * 8] = vC;
    }
    for (int i = 0; i < 32; i++) {
        const int t = wid * 32 + i;
        const int slot = (i >> 3) ^ (lane & 3);
        XTl[(wid * 64 + lane) * 32 + slot * 8 + (i & 7)] = xcp[(long)t * 1664 + lane];
    }
    if (wid == 0) {
        const float d0 = dtp[(long)(2 * lane) * 24 + h];
        const float d1 = dtp[(long)(2 * lane + 1) * 24 + h];
        const float a0 = d0 * A, a1v = d1 * A;
        float sc = a0 + a1v;
#pragma unroll
        for (int o = 1; o < 64; o <<= 1) {
            const float pv = __shfl_up(sc, o);
            if (lane >= o) sc += pv;
        }
        const float tot = __shfl(sc, 63);
        cum[2 * lane]     = sc - a1v;
        cum[2 * lane + 1] = sc;
        dtl[2 * lane]     = d0;
        dtl[2 * lane + 1] = d1;
        wl[2 * lane]      = __expf(tot - (sc - a1v)) * d0;
        wl[2 * lane + 1]  = __expf(tot - sc) * d1;
    }
    __syncthreads();

    const int wr1 = (wid >> 1) * 64, wc1 = (wid & 1) * 64;
    const int ck = (lk ^ (lrow & 3)) * 8;
    f32x4 a1[4][4];
#pragma unroll
    for (int m = 0; m < 4; m++)
#pragma unroll
        for (int n = 0; n < 4; n++) a1[m][n] = f32x4{0.f, 0.f, 0.f, 0.f};
#pragma unroll
    for (int kst = 0; kst < 2; kst++) {
        bf16x8 ca[4], bb[4];
#pragma unroll
        for (int m = 0; m < 4; m++)
            ca[m] = *(const bf16x8*)(const void*)&Cl[(kst * 128 + wr1 + m * 16 + lrow) * 32 + ck];
#pragma unroll
        for (int n = 0; n < 4; n++)
            bb[n] = *(const bf16x8*)(const void*)&Bl[(kst * 128 + wc1 + n * 16 + lrow) * 32 + ck];
#pragma unroll
        for (int m = 0; m < 4; m++)
#pragma unroll
            for (int n = 0; n < 4; n++)
                a1[m][n] = __builtin_amdgcn_mfma_f32_16x16x32_bf16(bb[n], ca[m], a1[m][n], 0, 0, 0);
    }
    __syncthreads();

#pragma unroll
    for (int m = 0; m < 4; m++) {
        const int t = wr1 + m * 16 + lrow;
        const float ct = cum[t];
        const int txor = (t & 3);
#pragma unroll
        for (int n = 0; n < 4; n++) {
            const int j0 = wc1 + n * 16 + lk * 4;
            const f32x4 cj = *(const f32x4*)&cum[j0];
            const f32x4 dj = *(const f32x4*)&dtl[j0];
            bf16x4 o;
#pragma unroll
            for (int jj = 0; jj < 4; jj++) {
                const int j = j0 + jj;
                float val = 0.f;
                if (j <= t) val = a1[m][n][jj] * __expf(ct - cj[jj]) * dj[jj];
                o[jj] = (__bf16)val;
            }
            const int jst = j0 >> 5, jc = (j0 >> 3) & 3, je = j0 & 7;
            *(bf16x4*)(void*)&Ml[(jst * 128 + t) * 32 + ((jc ^ txor) * 8) + je] = o;
        }
    }
    __syncthreads();

    const int wr2 = (wid >> 1) * 64, wc2 = (wid & 1) * 32;
    f32x4 a2[4][2];
#pragma unroll
    for (int m = 0; m < 4; m++)
#pragma unroll
        for (int n = 0; n < 2; n++) a2[m][n] = f32x4{0.f, 0.f, 0.f, 0.f};
#pragma unroll
    for (int kst = 0; kst < 4; kst++) {
        bf16x8 am[4], bn[2];
#pragma unroll
        for (int m = 0; m < 4; m++)
            am[m] = *(const bf16x8*)(const void*)&Ml[(kst * 128 + wr2 + m * 16 + lrow) * 32 + ck];
#pragma unroll
        for (int n = 0; n < 2; n++)
            bn[n] = *(const bf16x8*)(const void*)&XTl[(kst * 64 + wc2 + n * 16 + lrow) * 32 + ck];
#pragma unroll
        for (int m = 0; m < 4; m++)
#pragma unroll
            for (int n = 0; n < 2; n++)
                a2[m][n] = __builtin_amdgcn_mfma_f32_16x16x32_bf16(bn[n], am[m], a2[m][n], 0, 0, 0);
    }

#pragma unroll
    for (int m = 0; m < 4; m++) {
        const int t = wr2 + m * 16 + lrow;
#pragma unroll
        for (int n = 0; n < 2; n++) {
            const int p0 = wc2 + n * 16 + lk * 4;
            const bf16x4 x4 = *(const bf16x4*)(const void*)&xcp[(long)t * 1664 + p0];
            const bf16x4 z4 = *(const bf16x4*)(const void*)&zxp[(long)t * 3328 + p0];
            bf16x4 o;
#pragma unroll
            for (int jj = 0; jj < 4; jj++) {
                const float x = (float)x4[jj];
                const float zg = (float)z4[jj];
                const float y = (a2[m][n][jj] + Dh * x) * (zg / (1.f + __expf(-zg)));
                o[jj] = (__bf16)y;
            }
            *(bf16x4*)(void*)&xcp[(long)t * 1664 + p0] = o;
        }
    }

    if (hout) {
        __syncthreads();
        for (int i = 0; i < 32; i++) {
            const int j = wid * 32 + i;
            const int slot = (i >> 3) ^ (lane & 3);
            BTl[(wid * 64 + lane) * 32 + slot * 8 + (j & 7)] = bcp[(long)j * 128 + lane];
        }
        __syncthreads();
        const int wrp = (wid >> 1) * 32, wcs = (wid & 1) * 32;
        f32x4 a3[2][2];
#pragma unroll
        for (int m = 0; m < 2; m++)
#pragma unroll
            for (int n = 0; n < 2; n++) a3[m][n] = f32x4{0.f, 0.f, 0.f, 0.f};
#pragma unroll
        for (int kst = 0; kst < 4; kst++) {
            const int jb = kst * 32 + lk * 8;
            const f32x4 wa = *(const f32x4*)&wl[jb];
            const f32x4 wb = *(const f32x4*)&wl[jb + 4];
            bf16x8 xw[2], bn[2];
#pragma unroll
            for (int m = 0; m < 2; m++) {
                bf16x8 xr = *(const bf16x8*)(const void*)&XTl[(kst * 64 + wrp + m * 16 + lrow) * 32 + ck];
                bf16x8 t;
#pragma unroll
                for (int e = 0; e < 4; e++) t[e] = (__bf16)((float)xr[e] * wa[e]);
#pragma unroll
                for (int e = 0; e < 4; e++) t[4 + e] = (__bf16)((float)xr[4 + e] * wb[e]);
                xw[m] = t;
            }
#pragma unroll
            for (int n = 0; n < 2; n++)
                bn[n] = *(const bf16x8*)(const void*)&BTl[(kst * 64 + wcs + n * 16 + lrow) * 32 + ck];
#pragma unroll
            for (int m = 0; m < 2; m++)
#pragma unroll
                for (int n = 0; n < 2; n++)
                    a3[m][n] = __builtin_amdgcn_mfma_f32_16x16x32_bf16(xw[m], bn[n], a3[m][n], 0, 0, 0);
        }
        float* hp = hout + ((long)(bt0 + btl) * 24 + h) * 4096;
#pragma unroll
        for (int m = 0; m < 2; m++) {
            const int pb = wrp + m * 16 + lk * 4;
#pragma unroll
            for (int n = 0; n < 2; n++) {
                const int s = wcs + n * 16 + lrow;
#pragma unroll
                for (int jj = 0; jj < 4; jj++)
                    hp[(long)(pb + jj) * 64 + s] = a3[m][n][jj];
            }
        }
    }
}

// ---------------- host orchestration ----------------
extern "C" void kernel_launch(void* const* d_in, const int* in_sizes, int n_in,
                              void* d_out, int out_size, void* d_ws, size_t ws_size,
                              hipStream_t stream)
{
    const float* precepts  = (const float*)d_in[0];
    const float* actions   = (const float*)d_in[1];
    const float* attn_n1   = (const float*)d_in[2];
    const float* Wq        = (const float*)d_in[3];
    const float* Wk        = (const float*)d_in[4];
    const float* Wv        = (const float*)d_in[5];
    const float* Wo        = (const float*)d_in[6];
    const float* attn_n2   = (const float*)d_in[7];
    const float* ffn_w1    = (const float*)d_in[8];
    const float* ffn_b1    = (const float*)d_in[9];
    const float* ffn_w2    = (const float*)d_in[10];
    const float* ffn_b2    = (const float*)d_in[11];
    const float* ssm_norm  = (const float*)d_in[12];
    const float* in_proj   = (const float*)d_in[13];
    const float* conv_w    = (const float*)d_in[14];
    const float* conv_b    = (const float*)d_in[15];
    const float* dt_bias   = (const float*)d_in[16];
    const float* A_log     = (const float*)d_in[17];
    const float* D_skip    = (const float*)d_in[18];
    const float* mamba_nw  = (const float*)d_in[19];
    const float* out_proj  = (const float*)d_in[20];
    const float* proj_w    = (const float*)d_in[21];
    const float* proj_b    = (const float*)d_in[22];

    float* out  = (float*)d_out;
    __hip_bfloat16* Pb = (__hip_bfloat16*)(out + HALF);  // bf16 residual; dead before h_last
    float* hout = out + HALF;

    __hip_bfloat16* wb = (__hip_bfloat16*)d_ws;
    long wo = 0;
    auto walloc = [&](long els) { __hip_bfloat16* p = wb + wo; wo += els; return p; };
    __hip_bfloat16* WqkvT = walloc(4L * 2304 * 768);
    __hip_bfloat16* W1T   = walloc(4L * 3072 * 768);
    __hip_bfloat16* W2T   = walloc(4L * 768 * 3072);
    __hip_bfloat16* inT   = walloc(4L * 3328 * 768);
    __hip_bfloat16* outT  = walloc(4L * 768 * 1536);
    __hip_bfloat16* projT = walloc(768L * 768);
    __hip_bfloat16* WoT   = walloc(4L * 768 * 768);
    __hip_bfloat16* Zb    = walloc(TOK * 768);           // bf16 z residual (persistent)
    char* pbase = (char*)(wb + ((wo + 255) & ~255L));
    const size_t used_w = (size_t)(pbase - (char*)d_ws);
    const size_t avail = ws_size > used_w ? ws_size - used_w : 0;

    int CB = 512;
    while (CB > 8 && (unsigned long long)CB * 884736ull > avail) CB >>= 1;
    int CBT = 256;
    while (CBT > 2 && (unsigned long long)CBT * 1912832ull > avail) CBT >>= 1;

    auto gemm = [&](const __hip_bfloat16* A, const __hip_bfloat16* BT, const float* bias,
                    void* C, int ldc, int M, int N, int Npad, int K, int flags, int moff) {
        const bool fit256 = (M & 255) == 0 && (Npad & 255) == 0 && (K & 63) == 0;
        const long nwg256 = fit256 ? ((long)(M / 256) * (Npad / 256)) : 0;
        if (fit256 && nwg256 >= 512) {
            dim3 g(Npad / 256, M / 256);
            hipLaunchKernelGGL(gemm256, g, dim3(512), 0, stream,
                               A, BT, bias, C, ldc, M, N, K, flags, moff);
        } else {
            dim3 g(Npad / 128, M / 128);
            hipLaunchKernelGGL(gemm_bf16, g, dim3(256), 0, stream,
                               A, BT, bias, C, ldc, M, N, K, flags, moff);
        }
    };
    auto cvtT = [&](const float* W, __hip_bfloat16* WT, int K, int N, int Npad) {
        dim3 g((Npad + 31) / 32, (K + 31) / 32);
        hipLaunchKernelGGL(convT_kernel, g, dim3(256), 0, stream, W, WT, K, N, Npad);
    };
    auto cvt = [&](const float* x, __hip_bfloat16* y, long n) {
        long n4 = n / 4;
        hipLaunchKernelGGL(cvt_kernel, dim3((n4 + 255) / 256), dim3(256), 0, stream,
                           (const float4*)x, (ushort4*)y, n4);
    };
    auto rmsB = [&](const __hip_bfloat16* x, const float* w, __hip_bfloat16* o, int D, int xs, int os, long rows) {
        hipLaunchKernelGGL(rmsnorm_b16, dim3((rows + 3) / 4), dim3(256), 0, stream,
                           x, w, o, D, xs, os, rows);
    };

    // ---- weight conversion ----
    for (int l = 0; l < 4; l++) {
        cvtT(Wq + (long)l * 589824, WqkvT + (long)l * 2304 * 768,                768, 768, 768);
        cvtT(Wk + (long)l * 589824, WqkvT + (long)l * 2304 * 768 +  768L * 768,  768, 768, 768);
        cvtT(Wv + (long)l * 589824, WqkvT + (long)l * 2304 * 768 + 1536L * 768,  768, 768, 768);
        cvtT(Wo + (long)l * 589824, WoT + (long)l * 589824, 768, 768, 768);
        cvtT(ffn_w1 + (long)l * 2359296, W1T + (long)l * 2359296, 768, 3072, 3072);
        cvtT(ffn_w2 + (long)l * 2359296, W2T + (long)l * 2359296, 3072, 768, 768);
    }
    for (int m = 0; m < 4; m++) {
        cvtT(in_proj + (long)m * 768 * 3224, inT + (long)m * 3328 * 768, 768, 3224, 3328);
        cvtT(out_proj + (long)m * 1536 * 768, outT + (long)m * 768 * 1536, 1536, 768, 768);
    }
    cvtT(proj_w, projT, 768, 768, 768);

    // ---- attention stack (bf16 residual in Pb) ----
    cvt(precepts, Pb, HALF);
    {
        const long rA = (long)CB * 64;
        __hip_bfloat16* bufA   = (__hip_bfloat16*)pbase;        // rA x 768
        __hip_bfloat16* actB   = bufA + rA * 768;               // rA x 768
        __hip_bfloat16* bufQKV = actB + rA * 768;               // rA x 2304
        __hip_bfloat16* bufH   = bufQKV + rA * 2304;            // rA x 3072
        const int nac = 512 / CB;
        const int Mr = (int)rA;
        if (nac == 1) cvt(actions, actB, rA * 768);
        for (int layer = 0; layer < 4; layer++) {
            const bool cross = ((layer + 1) % 2) == 0;
            for (int c = 0; c < nac; c++) {
                const long tok0 = (long)c * rA;
                __hip_bfloat16* Pc = Pb + tok0 * 768;
                rmsB(Pc, attn_n1 + layer * 768, bufA, 768, 768, 768, Mr);
                if (!cross) {
                    gemm(bufA, WqkvT + (long)layer * 2304 * 768, nullptr, bufQKV, 2304,
                         Mr, 2304, 2304, 768, FLAG_BF16, 0);
                } else {
                    if (nac != 1) cvt(actions + tok0 * 768, actB, rA * 768);
                    gemm(bufA, WqkvT + (long)layer * 2304 * 768, nullptr, bufQKV, 2304,
                         Mr, 768, 768, 768, FLAG_BF16, 0);
                    gemm(actB, WqkvT + (long)layer * 2304 * 768 + 768L * 768, nullptr,
                         bufQKV + 768, 2304, Mr, 1536, 1536, 768, FLAG_BF16, 0);
                }
                hipLaunchKernelGGL(attn_kernel, dim3(CB * 8), dim3(256), 0, stream,
                                   bufQKV, bufA);
                gemm(bufA, WoT + (long)layer * 589824, nullptr, Pc, 768,
                     Mr, 768, 768, 768, FLAG_ACC | FLAG_BF16, 0);
                rmsB(Pc, attn_n2 + layer * 768, bufA, 768, 768, 768, Mr);
                gemm(bufA, W1T + (long)layer * 2359296, ffn_b1 + layer * 3072, bufH, 3072,
                     Mr, 3072, 3072, 768, FLAG_GELU | FLAG_BF16, 0);
                gemm(bufH, W2T + (long)layer * 2359296, ffn_b2 + layer * 768, Pc, 768,
                     Mr, 768, 768, 3072, FLAG_ACC | FLAG_BF16, 0);
            }
        }
    }

    // ---- transpose to SSM layout (bf16 -> bf16) ----
    hipLaunchKernelGGL(transpose_kernel, dim3((int)((HALF / 4 + 255) / 256)), dim3(256), 0, stream, Pb, Zb);

    // ---- mamba blocks (bf16 residual in Zb) ----
    {
        const long rM = (long)CBT * 128;
        __hip_bfloat16* xn  = (__hip_bfloat16*)pbase;            // rM x 768
        __hip_bfloat16* zx  = xn + rM * 768;                     // rM x 3328
        float*          dtf = (float*)(zx + rM * 3328);          // rM x 24
        __hip_bfloat16* xc  = (__hip_bfloat16*)(dtf + rM * 24);  // rM x 1664
        __hip_bfloat16* yb  = xc + rM * 1664;                    // rM x 1536
        __hip_bfloat16* bcB = yb + rM * 1536;                    // rM x 128
        const int nmc = 256 / CBT;
        const int Mr = (int)rM;
        for (int m = 0; m < 4; m++) {
            for (int c = 0; c < nmc; c++) {
                __hip_bfloat16* Zc = Zb + (long)c * rM * 768;
                rmsB(Zc, ssm_norm + m * 768, xn, 768, 768, 768, Mr);
                gemm(xn, inT + (long)m * 3328 * 768, nullptr, zx, 3328,
                     Mr, 3224, 3328, 768, FLAG_BF16, 0);
                hipLaunchKernelGGL(conv_kernel, dim3((int)rM), dim3(256), 0, stream,
                                   zx, conv_w + m * 4 * 1664, conv_b + m * 1664, xc, bcB, rM);
                const long dtn = rM * 24;
                hipLaunchKernelGGL(dt_kernel, dim3((int)((dtn + 255) / 256)), dim3(256), 0, stream,
                                   zx, dt_bias + m * 24, dtf, dtn);
                hipLaunchKernelGGL(ssd_kernel, dim3(CBT * 24), dim3(256), 0, stream,
                                   zx, dtf, bcB, xc, A_log + m * 24, D_skip + m * 24,
                                   (m == 3) ? hout : nullptr, c * CBT);
                rmsB(xc, mamba_nw + m * 1536, yb, 1536, 1664, 1536, Mr);
                gemm(yb, outT + (long)m * 768 * 1536, nullptr, Zc, 768,
                     Mr, 768, 768, 1536, FLAG_ACC | FLAG_BF16, 0);
            }
        }
    }

    // ---- final projection: read Zb directly, permuted f32 epilogue ----
    gemm(Zb, projT, proj_b, out, 768, 32768, 768, 768, 768, FLAG_PERM, 0);
}

// Round 17
// 5767.759 us; speedup vs baseline: 1.0412x; 1.0412x over previous
//
#include <hip/hip_runtime.h>
#include <hip/hip_bf16.h>
#include <math.h>

// ---------------- model dims ----------------
constexpr long TOK  = 32768;            // B*N*T
constexpr long HALF = TOK * 768;
constexpr int FLAG_ACC = 1, FLAG_GELU = 2, FLAG_PERM = 4, FLAG_BF16 = 8;

typedef __bf16 bf16x8 __attribute__((ext_vector_type(8)));
typedef __bf16 bf16x4 __attribute__((ext_vector_type(4)));
typedef float  f32x4  __attribute__((ext_vector_type(4)));

__device__ __forceinline__ void gload_lds16(const void* g, void* l) {
    __builtin_amdgcn_global_load_lds(
        (const __attribute__((address_space(1))) void*)g,
        (__attribute__((address_space(3))) void*)l, 16, 0, 0);
}
__device__ __forceinline__ float bf2f(__hip_bfloat16 v) { return __bfloat162float(v); }

// ======== 256x256 GEMM, 2 phases/K-tile (32 MFMA/phase), counted vmcnt ========
__global__ __launch_bounds__(512, 2) void gemm256(
    const __hip_bfloat16* __restrict__ A,
    const __hip_bfloat16* __restrict__ BT,
    const float* __restrict__ bias,
    void* __restrict__ Cv, int ldc,
    int M, int N, int K, int flags, int moff)
{
    __shared__ __align__(16) __hip_bfloat16 As[2][256 * 64];   // 64 KB
    __shared__ __align__(16) __hip_bfloat16 Bs[2][256 * 64];   // 64 KB
    const int tid = threadIdx.x;
    const int wid = tid >> 6, lane = tid & 63;
    const int wm = wid >> 2, wn = wid & 3;       // 2 x 4 wave grid
    const int lrow = lane & 15, lk = lane >> 4;
    // bijective XCD swizzle (m204)
    const int nwg = gridDim.x * gridDim.y;
    const int orig = blockIdx.y * gridDim.x + blockIdx.x;
    const int q8 = nwg >> 3, r8 = nwg & 7;
    const int xcd = orig & 7, off = orig >> 3;
    const int wgid = (xcd < r8 ? xcd * (q8 + 1) : r8 * (q8 + 1) + (xcd - r8) * q8) + off;
    const int bm = (wgid / gridDim.x) * 256, bn = (wgid % gridDim.x) * 256;
    const int nk = K >> 6;

    f32x4 acc[4][8];   // [nf][mf]; lane: row=lrow, 4 consecutive cols (lk*4)
#pragma unroll
    for (int nf = 0; nf < 4; nf++)
#pragma unroll
        for (int mf = 0; mf < 8; mf++) acc[nf][mf] = f32x4{0.f, 0.f, 0.f, 0.f};

    bf16x8 Af[4][2];   // current m-half quad frags x ks
    bf16x8 B0[2][2];   // n-frags 0-1 x ks (live whole K-tile)
    bf16x8 B1[2][2];   // n-frags 2-3 x ks (live whole K-tile)

    auto stage = [&](int kt, int which) {   // which: 0=A0,1=A1,2=B0,3=B1
        if (kt >= nk) return;
        const int dbuf = kt & 1;
        __hip_bfloat16* lbase = (which >= 2 ? &Bs[dbuf][0] : &As[dbuf][0]) + (which & 1) * 8192;
        const __hip_bfloat16* g = (which >= 2 ? BT : A);
        const int trow = (which >= 2 ? bn : bm) + (which & 1) * 128;
#pragma unroll
        for (int i = 0; i < 2; i++) {
            const int slot = i * 512 + tid;          // 0..1023 (16B units)
            const int rl = slot >> 3, ch = slot & 7;
            const int sc = (ch ^ (rl & 7)) * 8;      // inverse-swizzled source col
            const long src = (long)(trow + rl) * K + (long)kt * 64 + sc;
            char* l = (char*)lbase + (i * 512 + wid * 64) * 16;   // wave-uniform base
            gload_lds16(g + src, l);
        }
    };
    auto readA = [&](int dbuf, int mh) {
#pragma unroll
        for (int mq = 0; mq < 4; mq++)
#pragma unroll
            for (int ks = 0; ks < 2; ks++) {
                const int r = wm * 128 + mh * 64 + mq * 16 + lrow;
                const int ch = ((ks * 4 + lk) ^ (r & 7)) * 8;
                Af[mq][ks] = *(const bf16x8*)(const void*)&As[dbuf][r * 64 + ch];
            }
    };
    auto readB0 = [&](int dbuf) {
#pragma unroll
        for (int nf = 0; nf < 2; nf++)
#pragma unroll
            for (int ks = 0; ks < 2; ks++) {
                const int r = wn * 64 + nf * 16 + lrow;
                const int ch = ((ks * 4 + lk) ^ (r & 7)) * 8;
                B0[nf][ks] = *(const bf16x8*)(const void*)&Bs[dbuf][r * 64 + ch];
            }
    };
    auto readB1 = [&](int dbuf) {
#pragma unroll
        for (int nf = 0; nf < 2; nf++)
#pragma unroll
            for (int ks = 0; ks < 2; ks++) {
                const int r = wn * 64 + (2 + nf) * 16 + lrow;
                const int ch = ((ks * 4 + lk) ^ (r & 7)) * 8;
                B1[nf][ks] = *(const bf16x8*)(const void*)&Bs[dbuf][r * 64 + ch];
            }
    };

    // ---- prologue: K-tile 0 complete + B-halves of K-tile 1; leave 4 in flight ----
    stage(0, 0); stage(0, 1); stage(0, 2); stage(0, 3);
    stage(1, 2); stage(1, 3);
    asm volatile("s_waitcnt vmcnt(4)" ::: "memory");
    __builtin_amdgcn_s_barrier();

    for (int kt = 0; kt < nk; kt++) {
        const int cur = kt & 1;
        // ---- Phase A: mh0 x all nf (32 MFMA); stage A-halves of kt+1 -> other dbuf ----
        readA(cur, 0); readB0(cur); readB1(cur);
        stage(kt + 1, 0); stage(kt + 1, 1);
        __builtin_amdgcn_s_barrier();
        __builtin_amdgcn_s_setprio(1);
#pragma unroll
        for (int ks = 0; ks < 2; ks++) {
#pragma unroll
            for (int nf = 0; nf < 2; nf++)
#pragma unroll
                for (int mq = 0; mq < 4; mq++)
                    acc[nf][mq] = __builtin_amdgcn_mfma_f32_16x16x32_bf16(B0[nf][ks], Af[mq][ks], acc[nf][mq], 0, 0, 0);
#pragma unroll
            for (int nf = 0; nf < 2; nf++)
#pragma unroll
                for (int mq = 0; mq < 4; mq++)
                    acc[2 + nf][mq] = __builtin_amdgcn_mfma_f32_16x16x32_bf16(B1[nf][ks], Af[mq][ks], acc[2 + nf][mq], 0, 0, 0);
        }
        __builtin_amdgcn_s_setprio(0);
        __builtin_amdgcn_s_barrier();
        // ---- Phase B: mh1 x all nf; stage B-halves of kt+2 -> cur dbuf (B consumed) ----
        readA(cur, 1);
        stage(kt + 2, 2); stage(kt + 2, 3);
        if (kt + 2 < nk) asm volatile("s_waitcnt vmcnt(4)" ::: "memory");
        else             asm volatile("s_waitcnt vmcnt(0)" ::: "memory");
        __builtin_amdgcn_s_barrier();
        __builtin_amdgcn_s_setprio(1);
#pragma unroll
        for (int ks = 0; ks < 2; ks++) {
#pragma unroll
            for (int nf = 0; nf < 2; nf++)
#pragma unroll
                for (int mq = 0; mq < 4; mq++)
                    acc[nf][4 + mq] = __builtin_amdgcn_mfma_f32_16x16x32_bf16(B0[nf][ks], Af[mq][ks], acc[nf][4 + mq], 0, 0, 0);
#pragma unroll
            for (int nf = 0; nf < 2; nf++)
#pragma unroll
                for (int mq = 0; mq < 4; mq++)
                    acc[2 + nf][4 + mq] = __builtin_amdgcn_mfma_f32_16x16x32_bf16(B1[nf][ks], Af[mq][ks], acc[2 + nf][4 + mq], 0, 0, 0);
        }
        __builtin_amdgcn_s_setprio(0);
        __builtin_amdgcn_s_barrier();
    }

    float* Cf = (float*)Cv;
    __hip_bfloat16* Cb = (__hip_bfloat16*)Cv;
    if (flags & FLAG_BF16) {
        // coalesced bf16 store via per-wave-private LDS (stride 176B: 2-way max aliasing)
        char* lw = (char*)&As[0][0] + (size_t)wid * (64 * 176);   // 11 KB/wave
        const int colg = bn + wn * 64;
#pragma unroll
        for (int half = 0; half < 2; half++) {
#pragma unroll
            for (int nf = 0; nf < 4; nf++) {
                const int col = nf * 16 + lk * 4;
                f32x4 b4 = f32x4{0.f, 0.f, 0.f, 0.f};
                if (bias) b4 = *(const f32x4*)&bias[colg + col];
#pragma unroll
                for (int m4 = 0; m4 < 4; m4++) {
                    const int row = m4 * 16 + lrow;
                    f32x4 v = acc[nf][half * 4 + m4] + b4;
                    if (flags & FLAG_GELU) {
#pragma unroll
                        for (int j = 0; j < 4; j++) {
                            const float x = v[j];
                            const float u = 1.5957691216057308f * (x + 0.044715f * x * x * x);
                            v[j] = x / (1.f + __expf(-u));
                        }
                    }
                    if (flags & FLAG_ACC) {   // bf16 read-modify-write residual
                        const long gr = (long)(bm + wm * 128 + half * 64 + row);
                        const bf16x4 old = *(const bf16x4*)(const void*)&Cb[gr * ldc + colg + col];
#pragma unroll
                        for (int j = 0; j < 4; j++) v[j] += (float)old[j];
                    }
                    bf16x4 o;
                    o[0] = (__bf16)v[0]; o[1] = (__bf16)v[1];
                    o[2] = (__bf16)v[2]; o[3] = (__bf16)v[3];
                    *(bf16x4*)(void*)(lw + row * 176 + col * 2) = o;
                }
            }
            asm volatile("s_waitcnt lgkmcnt(0)" ::: "memory");
#pragma unroll
            for (int rr = 0; rr < 8; rr++) {
                const int row = rr * 8 + (lane >> 3);
                const long gr = (long)(bm + wm * 128 + half * 64 + row);
                const bf16x8 d = *(const bf16x8*)(const void*)(lw + row * 176 + (lane & 7) * 16);
                *(bf16x8*)(void*)&Cb[gr * ldc + colg + (lane & 7) * 8] = d;
            }
            asm volatile("s_waitcnt lgkmcnt(0)" ::: "memory");
        }
    } else {
#pragma unroll
        for (int nf = 0; nf < 4; nf++) {
            const int gcb = bn + wn * 64 + nf * 16 + lk * 4;
            if (gcb >= N) continue;
            f32x4 b4 = f32x4{0.f, 0.f, 0.f, 0.f};
            if (bias) b4 = *(const f32x4*)&bias[gcb];
#pragma unroll
            for (int mf = 0; mf < 8; mf++) {
                const int gr = bm + wm * 128 + mf * 16 + lrow;
                f32x4 v = acc[nf][mf] + b4;
                if (flags & FLAG_GELU) {
#pragma unroll
                    for (int j = 0; j < 4; j++) {
                        const float x = v[j];
                        const float u = 1.5957691216057308f * (x + 0.044715f * x * x * x);
                        v[j] = x / (1.f + __expf(-u));
                    }
                }
                if (flags & FLAG_PERM) {
                    const int mg = moff + gr;
                    const int b_ = mg >> 13, t_ = (mg >> 7) & 63, n_ = mg & 127;
                    *(f32x4*)&Cf[(((long)(b_ * 128 + n_)) * 64 + t_) * ldc + gcb] = v;
                } else if (flags & FLAG_ACC) {
                    float* dst = &Cf[(long)gr * ldc + gcb];
                    f32x4 old = *(const f32x4*)dst;
                    *(f32x4*)dst = old + v;
                } else {
                    *(f32x4*)&Cf[(long)gr * ldc + gcb] = v;
                }
            }
        }
    }
}

// ---------------- bf16 MFMA GEMM: 128x128 fallback (non-qualifying shapes) -------
__global__ __launch_bounds__(256) void gemm_bf16(
    const __hip_bfloat16* __restrict__ A,
    const __hip_bfloat16* __restrict__ BT,
    const float* __restrict__ bias,
    void* __restrict__ Cv, int ldc,
    int M, int N, int K, int flags, int moff)
{
    __shared__ __hip_bfloat16 As[2][128 * 32];
    __shared__ __hip_bfloat16 Bs[2][128 * 32];
    const int tid = threadIdx.x;
    const int wv = tid >> 6, lane = tid & 63;
    const int nwg = gridDim.x * gridDim.y;
    const int orig = blockIdx.y * gridDim.x + blockIdx.x;
    const int q8 = nwg >> 3, r8 = nwg & 7;
    const int xcd = orig & 7, off = orig >> 3;
    const int wgid = (xcd < r8 ? xcd * (q8 + 1) : r8 * (q8 + 1) + (xcd - r8) * q8) + off;
    const int bm = (wgid / gridDim.x) * 128, bn = (wgid % gridDim.x) * 128;
    const int wr = (wv >> 1) * 64, wc = (wv & 1) * 64;
    const int lrow = lane & 15, lk = lane >> 4;
    const int ck = (lk ^ (lrow & 3) ^ ((lrow >> 2) & 3)) * 8;

    f32x4 acc[4][4];
#pragma unroll
    for (int n = 0; n < 4; n++)
#pragma unroll
        for (int m = 0; m < 4; m++) acc[n][m] = f32x4{0.f, 0.f, 0.f, 0.f};

    const int nk = K >> 5;
    auto stage = [&](int kt, int buf) {
#pragma unroll
        for (int i = 0; i < 2; i++) {
            const int lin = i * 256 + tid;
            const int row = lin >> 2;
            const int ks  = (((lin & 3) ^ (row & 3) ^ ((row >> 2) & 3)) * 8);
            const long asrc = (long)(bm + row) * K + kt * 32 + ks;
            const long bsrc = (long)(bn + row) * K + kt * 32 + ks;
            char* la = (char*)&As[buf][0] + (i * 256 + wv * 64) * 16;
            char* lb = (char*)&Bs[buf][0] + (i * 256 + wv * 64) * 16;
            gload_lds16(A + asrc, la);
            gload_lds16(BT + bsrc, lb);
        }
    };

    stage(0, 0);
    __syncthreads();
    for (int kt = 0; kt < nk; kt++) {
        const int cur = kt & 1;
        if (kt + 1 < nk) stage(kt + 1, cur ^ 1);
        bf16x8 af[4], bfr[4];
#pragma unroll
        for (int m = 0; m < 4; m++) {
            af[m]  = *(const bf16x8*)(const void*)&As[cur][(wr + m * 16 + lrow) * 32 + ck];
            bfr[m] = *(const bf16x8*)(const void*)&Bs[cur][(wc + m * 16 + lrow) * 32 + ck];
        }
#pragma unroll
        for (int n = 0; n < 4; n++)
#pragma unroll
            for (int m = 0; m < 4; m++)
                acc[n][m] = __builtin_amdgcn_mfma_f32_16x16x32_bf16(bfr[n], af[m], acc[n][m], 0, 0, 0);
        __syncthreads();
    }

    float* Cf = (float*)Cv;
    __hip_bfloat16* Cb = (__hip_bfloat16*)Cv;
#pragma unroll
    for (int n = 0; n < 4; n++) {
        const int gcb = bn + wc + n * 16 + lk * 4;
        if (gcb >= N) continue;
        f32x4 b4 = f32x4{0.f, 0.f, 0.f, 0.f};
        if (bias) b4 = *(const f32x4*)&bias[gcb];
#pragma unroll
        for (int m = 0; m < 4; m++) {
            const int gr = bm + wr + m * 16 + lrow;
            f32x4 v = acc[n][m] + b4;
            if (flags & FLAG_GELU) {
#pragma unroll
                for (int j = 0; j < 4; j++) {
                    const float x = v[j];
                    const float u = 1.5957691216057308f * (x + 0.044715f * x * x * x);
                    v[j] = x / (1.f + __expf(-u));
                }
            }
            if (flags & FLAG_PERM) {
                const int mg = moff + gr;
                const int b_ = mg >> 13, t_ = (mg >> 7) & 63, n_ = mg & 127;
                *(f32x4*)&Cf[(((long)(b_ * 128 + n_)) * 64 + t_) * ldc + gcb] = v;
            } else if (flags & FLAG_BF16) {
                if (flags & FLAG_ACC) {
                    const bf16x4 old = *(const bf16x4*)(const void*)&Cb[(long)gr * ldc + gcb];
#pragma unroll
                    for (int j = 0; j < 4; j++) v[j] += (float)old[j];
                }
                __hip_bfloat16 o0 = __float2bfloat16(v[0]), o1 = __float2bfloat16(v[1]);
                __hip_bfloat16 o2 = __float2bfloat16(v[2]), o3 = __float2bfloat16(v[3]);
                ushort4 o = { *(ushort*)&o0, *(ushort*)&o1, *(ushort*)&o2, *(ushort*)&o3 };
                *(ushort4*)&Cb[(long)gr * ldc + gcb] = o;
            } else if (flags & FLAG_ACC) {
                float* dst = &Cf[(long)gr * ldc + gcb];
                f32x4 old = *(const f32x4*)dst;
                *(f32x4*)dst = old + v;
            } else {
                *(f32x4*)&Cf[(long)gr * ldc + gcb] = v;
            }
        }
    }
}

// ---------------- weight transpose-convert: W (KxN f32) -> WT (Npad x K bf16) ----
__global__ void convT_kernel(const float* __restrict__ W, __hip_bfloat16* __restrict__ WT,
                             int K, int N, int Npad)
{
    __shared__ float t[32][33];
    const int k0 = blockIdx.y * 32, n0 = blockIdx.x * 32;
    const int tx = threadIdx.x & 31, ty = threadIdx.x >> 5;
#pragma unroll
    for (int i = 0; i < 4; i++) {
        int k = k0 + ty + i * 8, n = n0 + tx;
        t[ty + i * 8][tx] = (k < K && n < N) ? W[(long)k * N + n] : 0.f;
    }
    __syncthreads();
#pragma unroll
    for (int i = 0; i < 4; i++) {
        int n = n0 + ty + i * 8, k = k0 + tx;
        if (n < Npad && k < K) WT[(long)n * K + k] = __float2bfloat16(t[tx][ty + i * 8]);
    }
}

// ---------------- f32 -> bf16 elementwise ----------------
__global__ void cvt_kernel(const float4* __restrict__ x, ushort4* __restrict__ y, long n4)
{
    long i = (long)blockIdx.x * 256 + threadIdx.x;
    if (i >= n4) return;
    float4 v = x[i];
    __hip_bfloat16 a = __float2bfloat16(v.x), b = __float2bfloat16(v.y);
    __hip_bfloat16 c = __float2bfloat16(v.z), d = __float2bfloat16(v.w);
    ushort4 o = { *(ushort*)&a, *(ushort*)&b, *(ushort*)&c, *(ushort*)&d };
    y[i] = o;
}

// ---------------- RMSNorm, wave-per-row, vectorized bf16 input ----------------
__global__ void rmsnorm_b16(const __hip_bfloat16* __restrict__ x, const float* __restrict__ w,
                            __hip_bfloat16* __restrict__ out, int D, int xs, int os, long nrows)
{
    const int wv = threadIdx.x >> 6, lane = threadIdx.x & 63;
    const long row = (long)blockIdx.x * 4 + wv;
    if (row >= nrows) return;
    const __hip_bfloat16* xr = x + row * xs;
    const int it = D >> 8;
    float ss = 0.f;
    for (int i = 0; i < it; i++) {
        const bf16x4 v = *(const bf16x4*)(const void*)&xr[(i * 64 + lane) * 4];
#pragma unroll
        for (int e = 0; e < 4; e++) { const float f = (float)v[e]; ss += f * f; }
    }
    for (int o = 32; o; o >>= 1) ss += __shfl_xor(ss, o);
    const float sc = rsqrtf(ss / D + 1e-5f);
    __hip_bfloat16* orow = out + row * os;
    for (int i = 0; i < it; i++) {
        const int e = (i * 64 + lane) * 4;
        const bf16x4 v = *(const bf16x4*)(const void*)&xr[e];
        const float4 g = *(const float4*)&w[e];
        bf16x4 o;
        o[0] = (__bf16)((float)v[0] * sc * g.x); o[1] = (__bf16)((float)v[1] * sc * g.y);
        o[2] = (__bf16)((float)v[2] * sc * g.z); o[3] = (__bf16)((float)v[3] * sc * g.w);
        *(bf16x4*)(void*)&orow[e] = o;
    }
}

// ---------------- fused attention, MFMA version: block per (batch, head) --------
__global__ __launch_bounds__(256) void attn_kernel(
    const __hip_bfloat16* __restrict__ QKV, __hip_bfloat16* __restrict__ O)
{
    __shared__ __align__(16) __hip_bfloat16 Qs[3 * 64 * 32];
    __shared__ __align__(16) __hip_bfloat16 Ks[3 * 64 * 32];
    __shared__ __align__(16) __hip_bfloat16 VT[2 * 96 * 32];
    __shared__ __align__(16) __hip_bfloat16 Ps[2 * 64 * 32];
    const int tid = threadIdx.x;
    const int wid = tid >> 6, lane = tid & 63;
    const int lrow = lane & 15, lk = lane >> 4;
    const int b = blockIdx.x >> 3, h = blockIdx.x & 7;
    const long base = (long)b * 64 * 2304 + h * 96;

#pragma unroll
    for (int i = 0; i < 3; i++) {
        const int v = i * 256 + tid;
        const int r = v / 12, c8 = v - r * 12;
        const int kst = c8 >> 2, ch = c8 & 3, slot = ch ^ (r & 3);
        const bf16x8 q = *(const bf16x8*)(const void*)&QKV[base + (long)r * 2304 + c8 * 8];
        const bf16x8 k = *(const bf16x8*)(const void*)&QKV[base + (long)r * 2304 + 768 + c8 * 8];
        *(bf16x8*)(void*)&Qs[(kst * 64 + r) * 32 + slot * 8] = q;
        *(bf16x8*)(void*)&Ks[(kst * 64 + r) * 32 + slot * 8] = k;
    }
    for (int i = 0; i < 16; i++) {
        const int k = wid * 16 + i;
        const __hip_bfloat16* vrow = &QKV[base + (long)k * 2304 + 1536];
        const int sb = (k >> 3) & 3, khi = k >> 5, klo = k & 7;
        {
            const int d = lane;
            VT[(khi * 96 + d) * 32 + ((sb ^ (d & 3)) * 8) + klo] = vrow[d];
        }
        if (lane < 32) {
            const int d = 64 + lane;
            VT[(khi * 96 + d) * 32 + ((sb ^ (d & 3)) * 8) + klo] = vrow[d];
        }
    }
    __syncthreads();

    const int ck = (lk ^ (lrow & 3)) * 8;
    f32x4 s[4];
#pragma unroll
    for (int n = 0; n < 4; n++) s[n] = f32x4{0.f, 0.f, 0.f, 0.f};
#pragma unroll
    for (int kst = 0; kst < 3; kst++) {
        const bf16x8 qf = *(const bf16x8*)(const void*)&Qs[(kst * 64 + wid * 16 + lrow) * 32 + ck];
#pragma unroll
        for (int n = 0; n < 4; n++) {
            const bf16x8 kf = *(const bf16x8*)(const void*)&Ks[(kst * 64 + n * 16 + lrow) * 32 + ck];
            s[n] = __builtin_amdgcn_mfma_f32_16x16x32_bf16(qf, kf, s[n], 0, 0, 0);
        }
    }
    const float scale = 0.102062072615966f;
#pragma unroll
    for (int n = 0; n < 4; n++) s[n] *= scale;
    float inv[4];
#pragma unroll
    for (int j = 0; j < 4; j++) {
        float mx = fmaxf(fmaxf(s[0][j], s[1][j]), fmaxf(s[2][j], s[3][j]));
        mx = fmaxf(mx, __shfl_xor(mx, 1));
        mx = fmaxf(mx, __shfl_xor(mx, 2));
        mx = fmaxf(mx, __shfl_xor(mx, 4));
        mx = fmaxf(mx, __shfl_xor(mx, 8));
        float sum = 0.f;
#pragma unroll
        for (int n = 0; n < 4; n++) { s[n][j] = __expf(s[n][j] - mx); sum += s[n][j]; }
        sum += __shfl_xor(sum, 1);
        sum += __shfl_xor(sum, 2);
        sum += __shfl_xor(sum, 4);
        sum += __shfl_xor(sum, 8);
        inv[j] = 1.f / sum;
    }
#pragma unroll
    for (int n = 0; n < 4; n++) {
        const int k = n * 16 + lrow;
        const int kst = n >> 1, kc = ((n & 1) << 1) + (lrow >> 3), ke = lrow & 7;
#pragma unroll
        for (int j = 0; j < 4; j++) {
            const int q = wid * 16 + lk * 4 + j;
            Ps[(kst * 64 + q) * 32 + ((kc ^ (q & 3)) * 8) + ke] = __float2bfloat16(s[n][j] * inv[j]);
        }
    }
    __syncthreads();

    const int wq = wid >> 1, wd = wid & 1;
    f32x4 y[3][2];
#pragma unroll
    for (int mv = 0; mv < 3; mv++)
#pragma unroll
        for (int np = 0; np < 2; np++) y[mv][np] = f32x4{0.f, 0.f, 0.f, 0.f};
#pragma unroll
    for (int ks = 0; ks < 2; ks++) {
        bf16x8 vf[3], pf[2];
#pragma unroll
        for (int mv = 0; mv < 3; mv++)
            vf[mv] = *(const bf16x8*)(const void*)&VT[(ks * 96 + wd * 48 + mv * 16 + lrow) * 32 + ck];
#pragma unroll
        for (int np = 0; np < 2; np++)
            pf[np] = *(const bf16x8*)(const void*)&Ps[(ks * 64 + wq * 32 + np * 16 + lrow) * 32 + ck];
#pragma unroll
        for (int mv = 0; mv < 3; mv++)
#pragma unroll
            for (int np = 0; np < 2; np++)
                y[mv][np] = __builtin_amdgcn_mfma_f32_16x16x32_bf16(vf[mv], pf[np], y[mv][np], 0, 0, 0);
    }
#pragma unroll
    for (int mv = 0; mv < 3; mv++) {
        const int d0 = wd * 48 + mv * 16 + lk * 4;
#pragma unroll
        for (int np = 0; np < 2; np++) {
            const int q = wq * 32 + np * 16 + lrow;
            bf16x4 o;
#pragma unroll
            for (int j = 0; j < 4; j++) o[j] = (__bf16)y[mv][np][j];
            *(bf16x4*)(void*)&O[(long)(b * 64 + q) * 768 + h * 96 + d0] = o;
        }
    }
}

// ------------ transpose p (B,N,T,D) -> z (B,T,N,D), bf16, 4 elems/thread --------
__global__ void transpose_kernel(const __hip_bfloat16* __restrict__ P, __hip_bfloat16* __restrict__ Z)
{
    long lin4 = (long)blockIdx.x * 256 + threadIdx.x;
    if (lin4 >= HALF / 4) return;
    int d4 = (int)(lin4 % 192);
    long rowz = lin4 / 192;
    int n = rowz & 127, t = (int)((rowz >> 7) & 63), b = (int)(rowz >> 13);
    long rowp = ((long)(b * 128 + n)) * 64 + t;
    const bf16x4 v = *(const bf16x4*)(const void*)&P[rowp * 768 + d4 * 4];
    *(bf16x4*)(void*)&Z[rowz * 768 + d4 * 4] = v;
}

// -------- causal depthwise conv + SiLU, vectorized: block per row, 8 chan/thread
__global__ __launch_bounds__(256) void conv_kernel(
    const __hip_bfloat16* __restrict__ zx, const float* __restrict__ cw,
    const float* __restrict__ cb, __hip_bfloat16* __restrict__ xc,
    __hip_bfloat16* __restrict__ bcB, long rows)
{
    const long r = blockIdx.x;
    const int tid = threadIdx.x;
    if (tid >= 208) return;
    const int c0 = tid * 8;
    const int n = (int)(r & 127);
    float acc[8];
    {
        const float4 b0 = *(const float4*)&cb[c0];
        const float4 b1 = *(const float4*)&cb[c0 + 4];
        acc[0] = b0.x; acc[1] = b0.y; acc[2] = b0.z; acc[3] = b0.w;
        acc[4] = b1.x; acc[5] = b1.y; acc[6] = b1.z; acc[7] = b1.w;
    }
#pragma unroll
    for (int k = 0; k < 4; k++) {
        if (n - 3 + k < 0) continue;
        const bf16x8 xv = *(const bf16x8*)(const void*)&zx[(r - 3 + k) * 3328 + 1536 + c0];
        const float4 w0 = *(const float4*)&cw[k * 1664 + c0];
        const float4 w1 = *(const float4*)&cw[k * 1664 + c0 + 4];
        acc[0] += w0.x * (float)xv[0]; acc[1] += w0.y * (float)xv[1];
        acc[2] += w0.z * (float)xv[2]; acc[3] += w0.w * (float)xv[3];
        acc[4] += w1.x * (float)xv[4]; acc[5] += w1.y * (float)xv[5];
        acc[6] += w1.z * (float)xv[6]; acc[7] += w1.w * (float)xv[7];
    }
    bf16x8 o;
#pragma unroll
    for (int e = 0; e < 8; e++) {
        const float s = acc[e] / (1.f + __expf(-acc[e]));
        o[e] = (__bf16)s;
    }
    if (c0 < 1536) *(bf16x8*)(void*)&xc[r * 1664 + c0] = o;
    else           *(bf16x8*)(void*)&bcB[r * 128 + (c0 - 1536)] = o;
}

// ---------------- dt = softplus(dt_raw + bias) -> f32 side buffer ----------------
__global__ void dt_kernel(const __hip_bfloat16* __restrict__ zx, const float* __restrict__ bias,
                          float* __restrict__ dtf, long count)
{
    long lin = (long)blockIdx.x * 256 + threadIdx.x;
    if (lin >= count) return;
    int h = (int)(lin % 24);
    long r = lin / 24;
    float v = bf2f(zx[r * 3328 + 3200 + h]) + bias[h];
    dtf[lin] = (v > 0.f) ? v + log1pf(expf(-v)) : log1pf(expf(v));
}

// ======== SSD kernel v2: wave-0 shfl scan, swapped-operand GEMMs, __expf ========
__global__ __launch_bounds__(256) void ssd_kernel(
    const __hip_bfloat16* __restrict__ zx0, const float* __restrict__ dtf0,
    const __hip_bfloat16* __restrict__ bcB0, __hip_bfloat16* __restrict__ xc0,
    const float* __restrict__ Alog, const float* __restrict__ Dskip,
    float* __restrict__ hout, int bt0)
{
    __shared__ __align__(16) char SM[50688];
    __hip_bfloat16* Cl  = (__hip_bfloat16*)SM;            // [2][128][32]
    __hip_bfloat16* Bl  = Cl + 8192;                      // [2][128][32]
    __hip_bfloat16* Ml  = (__hip_bfloat16*)SM;            // [4][128][32] overlays Cl+Bl
    __hip_bfloat16* XTl = (__hip_bfloat16*)(SM + 32768);  // [4][64][32]  (X^T: [p][t])
    __hip_bfloat16* BTl = (__hip_bfloat16*)SM;            // [4][64][32]  overlays Ml (hT)
    float* cum = (float*)(SM + 49152);                    // [128]
    float* dtl = cum + 128;                               // [128]
    float* wl  = dtl + 128;                               // [128]

    const int tid = threadIdx.x;
    const int wid = tid >> 6, lane = tid & 63;
    const int lrow = lane & 15, lk = lane >> 4;
    const int btl = blockIdx.x / 24, h = blockIdx.x % 24;
    const long rowbase = (long)btl * 128;

    const __hip_bfloat16* zxp = zx0 + rowbase * 3328 + h * 64;
    const float* dtp = dtf0 + rowbase * 24;
    const __hip_bfloat16* bcp = bcB0 + rowbase * 128;
    __hip_bfloat16* xcp = xc0 + rowbase * 1664 + h * 64;

    const float A  = -__expf(Alog[h]);
    const float Dh = Dskip[h];

#pragma unroll
    for (int i = 0; i < 4; i++) {
        const int v = tid + i * 256;
        const int row = v >> 3, c8 = v & 7;
        const int kst = c8 >> 2, ch = c8 & 3;
        const int slot = ch ^ (row & 3);
        bf16x8 vB = *(const bf16x8*)(const void*)&bcp[(long)row * 128 + c8 * 8];
        bf16x8 vC = *(const bf16x8*)(const void*)&bcp[(long)row * 128 + 64 + c8 * 8];
        *(bf16x8*)(void*)&Bl[(kst * 128 + row) * 32 + slot * 8] = vB;
        *(bf16x8*)(void*)&Cl[(kst * 128 + row) * 32 + slot * 8] = vC;
    }
    for (int i = 0; i < 32; i++) {
        const int t = wid * 32 + i;
        const int slot = (i >> 3) ^ (lane & 3);
        XTl[(wid * 64 + lane) * 32 + slot * 8 + (i & 7)] = xcp[(long)t * 1664 + lane];
    }
    if (wid == 0) {
        const float d0 = dtp[(long)(2 * lane) * 24 + h];
        const float d1 = dtp[(long)(2 * lane + 1) * 24 + h];
        const float a0 = d0 * A, a1v = d1 * A;
        float sc = a0 + a1v;
#pragma unroll
        for (int o = 1; o < 64; o <<= 1) {
            const float pv = __shfl_up(sc, o);
            if (lane >= o) sc += pv;
        }
        const float tot = __shfl(sc, 63);
        cum[2 * lane]     = sc - a1v;
        cum[2 * lane + 1] = sc;
        dtl[2 * lane]     = d0;
        dtl[2 * lane + 1] = d1;
        wl[2 * lane]      = __expf(tot - (sc - a1v)) * d0;
        wl[2 * lane + 1]  = __expf(tot - sc) * d1;
    }
    __syncthreads();

    const int wr1 = (wid >> 1) * 64, wc1 = (wid & 1) * 64;
    const int ck = (lk ^ (lrow & 3)) * 8;
    f32x4 a1[4][4];
#pragma unroll
    for (int m = 0; m < 4; m++)
#pragma unroll
        for (int n = 0; n < 4; n++) a1[m][n] = f32x4{0.f, 0.f, 0.f, 0.f};
#pragma unroll
    for (int kst = 0; kst < 2; kst++) {
        bf16x8 ca[4], bb[4];
#pragma unroll
        for (int m = 0; m < 4; m++)
            ca[m] = *(const bf16x8*)(const void*)&Cl[(kst * 128 + wr1 + m * 16 + lrow) * 32 + ck];
#pragma unroll
        for (int n = 0; n < 4; n++)
            bb[n] = *(const bf16x8*)(const void*)&Bl[(kst * 128 + wc1 + n * 16 + lrow) * 32 + ck];
#pragma unroll
        for (int m = 0; m < 4; m++)
#pragma unroll
            for (int n = 0; n < 4; n++)
                a1[m][n] = __builtin_amdgcn_mfma_f32_16x16x32_bf16(bb[n], ca[m], a1[m][n], 0, 0, 0);
    }
    __syncthreads();

#pragma unroll
    for (int m = 0; m < 4; m++) {
        const int t = wr1 + m * 16 + lrow;
        const float ct = cum[t];
        const int txor = (t & 3);
#pragma unroll
        for (int n = 0; n < 4; n++) {
            const int j0 = wc1 + n * 16 + lk * 4;
            const f32x4 cj = *(const f32x4*)&cum[j0];
            const f32x4 dj = *(const f32x4*)&dtl[j0];
            bf16x4 o;
#pragma unroll
            for (int jj = 0; jj < 4; jj++) {
                const int j = j0 + jj;
                float val = 0.f;
                if (j <= t) val = a1[m][n][jj] * __expf(ct - cj[jj]) * dj[jj];
                o[jj] = (__bf16)val;
            }
            const int jst = j0 >> 5, jc = (j0 >> 3) & 3, je = j0 & 7;
            *(bf16x4*)(void*)&Ml[(jst * 128 + t) * 32 + ((jc ^ txor) * 8) + je] = o;
        }
    }
    __syncthreads();

    const int wr2 = (wid >> 1) * 64, wc2 = (wid & 1) * 32;
    f32x4 a2[4][2];
#pragma unroll
    for (int m = 0; m < 4; m++)
#pragma unroll
        for (int n = 0; n < 2; n++) a2[m][n] = f32x4{0.f, 0.f, 0.f, 0.f};
#pragma unroll
    for (int kst = 0; kst < 4; kst++) {
        bf16x8 am[4], bn[2];
#pragma unroll
        for (int m = 0; m < 4; m++)
            am[m] = *(const bf16x8*)(const void*)&Ml[(kst * 128 + wr2 + m * 16 + lrow) * 32 + ck];
#pragma unroll
        for (int n = 0; n < 2; n++)
            bn[n] = *(const bf16x8*)(const void*)&XTl[(kst * 64 + wc2 + n * 16 + lrow) * 32 + ck];
#pragma unroll
        for (int m = 0; m < 4; m++)
#pragma unroll
            for (int n = 0; n < 2; n++)
                a2[m][n] = __builtin_amdgcn_mfma_f32_16x16x32_bf16(bn[n], am[m], a2[m][n], 0, 0, 0);
    }

#pragma unroll
    for (int m = 0; m < 4; m++) {
        const int t = wr2 + m * 16 + lrow;
#pragma unroll
        for (int n = 0; n < 2; n++) {
            const int p0 = wc2 + n * 16 + lk * 4;
            const bf16x4 x4 = *(const bf16x4*)(const void*)&xcp[(long)t * 1664 + p0];
            const bf16x4 z4 = *(const bf16x4*)(const void*)&zxp[(long)t * 3328 + p0];
            bf16x4 o;
#pragma unroll
            for (int jj = 0; jj < 4; jj++) {
                const float x = (float)x4[jj];
                const float zg = (float)z4[jj];
                const float y = (a2[m][n][jj] + Dh * x) * (zg / (1.f + __expf(-zg)));
                o[jj] = (__bf16)y;
            }
            *(bf16x4*)(void*)&xcp[(long)t * 1664 + p0] = o;
        }
    }

    if (hout) {
        __syncthreads();
        for (int i = 0; i < 32; i++) {
            const int j = wid * 32 + i;
            const int slot = (i >> 3) ^ (lane & 3);
            BTl[(wid * 64 + lane) * 32 + slot * 8 + (j & 7)] = bcp[(long)j * 128 + lane];
        }
        __syncthreads();
        const int wrp = (wid >> 1) * 32, wcs = (wid & 1) * 32;
        f32x4 a3[2][2];
#pragma unroll
        for (int m = 0; m < 2; m++)
#pragma unroll
            for (int n = 0; n < 2; n++) a3[m][n] = f32x4{0.f, 0.f, 0.f, 0.f};
#pragma unroll
        for (int kst = 0; kst < 4; kst++) {
            const int jb = kst * 32 + lk * 8;
            const f32x4 wa = *(const f32x4*)&wl[jb];
            const f32x4 wb = *(const f32x4*)&wl[jb + 4];
            bf16x8 xw[2], bn[2];
#pragma unroll
            for (int m = 0; m < 2; m++) {
                bf16x8 xr = *(const bf16x8*)(const void*)&XTl[(kst * 64 + wrp + m * 16 + lrow) * 32 + ck];
                bf16x8 t;
#pragma unroll
                for (int e = 0; e < 4; e++) t[e] = (__bf16)((float)xr[e] * wa[e]);
#pragma unroll
                for (int e = 0; e < 4; e++) t[4 + e] = (__bf16)((float)xr[4 + e] * wb[e]);
                xw[m] = t;
            }
#pragma unroll
            for (int n = 0; n < 2; n++)
                bn[n] = *(const bf16x8*)(const void*)&BTl[(kst * 64 + wcs + n * 16 + lrow) * 32 + ck];
#pragma unroll
            for (int m = 0; m < 2; m++)
#pragma unroll
                for (int n = 0; n < 2; n++)
                    a3[m][n] = __builtin_amdgcn_mfma_f32_16x16x32_bf16(xw[m], bn[n], a3[m][n], 0, 0, 0);
        }
        float* hp = hout + ((long)(bt0 + btl) * 24 + h) * 4096;
#pragma unroll
        for (int m = 0; m < 2; m++) {
            const int pb = wrp + m * 16 + lk * 4;
#pragma unroll
            for (int n = 0; n < 2; n++) {
                const int s = wcs + n * 16 + lrow;
#pragma unroll
                for (int jj = 0; jj < 4; jj++)
                    hp[(long)(pb + jj) * 64 + s] = a3[m][n][jj];
            }
        }
    }
}

// ---------------- host orchestration ----------------
extern "C" void kernel_launch(void* const* d_in, const int* in_sizes, int n_in,
                              void* d_out, int out_size, void* d_ws, size_t ws_size,
                              hipStream_t stream)
{
    const float* precepts  = (const float*)d_in[0];
    const float* actions   = (const float*)d_in[1];
    const float* attn_n1   = (const float*)d_in[2];
    const float* Wq        = (const float*)d_in[3];
    const float* Wk        = (const float*)d_in[4];
    const float* Wv        = (const float*)d_in[5];
    const float* Wo        = (const float*)d_in[6];
    const float* attn_n2   = (const float*)d_in[7];
    const float* ffn_w1    = (const float*)d_in[8];
    const float* ffn_b1    = (const float*)d_in[9];
    const float* ffn_w2    = (const float*)d_in[10];
    const float* ffn_b2    = (const float*)d_in[11];
    const float* ssm_norm  = (const float*)d_in[12];
    const float* in_proj   = (const float*)d_in[13];
    const float* conv_w    = (const float*)d_in[14];
    const float* conv_b    = (const float*)d_in[15];
    const float* dt_bias   = (const float*)d_in[16];
    const float* A_log     = (const float*)d_in[17];
    const float* D_skip    = (const float*)d_in[18];
    const float* mamba_nw  = (const float*)d_in[19];
    const float* out_proj  = (const float*)d_in[20];
    const float* proj_w    = (const float*)d_in[21];
    const float* proj_b    = (const float*)d_in[22];

    float* out  = (float*)d_out;
    __hip_bfloat16* Pb = (__hip_bfloat16*)(out + HALF);  // bf16 residual; dead before h_last
    float* hout = out + HALF;

    __hip_bfloat16* wb = (__hip_bfloat16*)d_ws;
    long wo = 0;
    auto walloc = [&](long els) { __hip_bfloat16* p = wb + wo; wo += els; return p; };
    __hip_bfloat16* WqkvT = walloc(4L * 2304 * 768);
    __hip_bfloat16* W1T   = walloc(4L * 3072 * 768);
    __hip_bfloat16* W2T   = walloc(4L * 768 * 3072);
    __hip_bfloat16* inT   = walloc(4L * 3328 * 768);
    __hip_bfloat16* outT  = walloc(4L * 768 * 1536);
    __hip_bfloat16* projT = walloc(768L * 768);
    __hip_bfloat16* WoT   = walloc(4L * 768 * 768);
    __hip_bfloat16* Zb    = walloc(TOK * 768);           // bf16 z residual (persistent)
    char* pbase = (char*)(wb + ((wo + 255) & ~255L));
    const size_t used_w = (size_t)(pbase - (char*)d_ws);
    const size_t avail = ws_size > used_w ? ws_size - used_w : 0;

    int CB = 512;
    while (CB > 8 && (unsigned long long)CB * 884736ull > avail) CB >>= 1;
    int CBT = 256;
    while (CBT > 2 && (unsigned long long)CBT * 1912832ull > avail) CBT >>= 1;

    auto gemm = [&](const __hip_bfloat16* A, const __hip_bfloat16* BT, const float* bias,
                    void* C, int ldc, int M, int N, int Npad, int K, int flags, int moff) {
        if ((M & 255) == 0 && (Npad & 255) == 0 && (K & 63) == 0) {
            dim3 g(Npad / 256, M / 256);
            hipLaunchKernelGGL(gemm256, g, dim3(512), 0, stream,
                               A, BT, bias, C, ldc, M, N, K, flags, moff);
        } else {
            dim3 g(Npad / 128, M / 128);
            hipLaunchKernelGGL(gemm_bf16, g, dim3(256), 0, stream,
                               A, BT, bias, C, ldc, M, N, K, flags, moff);
        }
    };
    auto cvtT = [&](const float* W, __hip_bfloat16* WT, int K, int N, int Npad) {
        dim3 g((Npad + 31) / 32, (K + 31) / 32);
        hipLaunchKernelGGL(convT_kernel, g, dim3(256), 0, stream, W, WT, K, N, Npad);
    };
    auto cvt = [&](const float* x, __hip_bfloat16* y, long n) {
        long n4 = n / 4;
        hipLaunchKernelGGL(cvt_kernel, dim3((n4 + 255) / 256), dim3(256), 0, stream,
                           (const float4*)x, (ushort4*)y, n4);
    };
    auto rmsB = [&](const __hip_bfloat16* x, const float* w, __hip_bfloat16* o, int D, int xs, int os, long rows) {
        hipLaunchKernelGGL(rmsnorm_b16, dim3((rows + 3) / 4), dim3(256), 0, stream,
                           x, w, o, D, xs, os, rows);
    };

    // ---- weight conversion ----
    for (int l = 0; l < 4; l++) {
        cvtT(Wq + (long)l * 589824, WqkvT + (long)l * 2304 * 768,                768, 768, 768);
        cvtT(Wk + (long)l * 589824, WqkvT + (long)l * 2304 * 768 +  768L * 768,  768, 768, 768);
        cvtT(Wv + (long)l * 589824, WqkvT + (long)l * 2304 * 768 + 1536L * 768,  768, 768, 768);
        cvtT(Wo + (long)l * 589824, WoT + (long)l * 589824, 768, 768, 768);
        cvtT(ffn_w1 + (long)l * 2359296, W1T + (long)l * 2359296, 768, 3072, 3072);
        cvtT(ffn_w2 + (long)l * 2359296, W2T + (long)l * 2359296, 3072, 768, 768);
    }
    for (int m = 0; m < 4; m++) {
        cvtT(in_proj + (long)m * 768 * 3224, inT + (long)m * 3328 * 768, 768, 3224, 3328);
        cvtT(out_proj + (long)m * 1536 * 768, outT + (long)m * 768 * 1536, 1536, 768, 768);
    }
    cvtT(proj_w, projT, 768, 768, 768);

    // ---- attention stack (bf16 residual in Pb) ----
    cvt(precepts, Pb, HALF);
    {
        const long rA = (long)CB * 64;
        __hip_bfloat16* bufA   = (__hip_bfloat16*)pbase;        // rA x 768
        __hip_bfloat16* actB   = bufA + rA * 768;               // rA x 768
        __hip_bfloat16* bufQKV = actB + rA * 768;               // rA x 2304
        __hip_bfloat16* bufH   = bufQKV + rA * 2304;            // rA x 3072
        const int nac = 512 / CB;
        const int Mr = (int)rA;
        if (nac == 1) cvt(actions, actB, rA * 768);
        for (int layer = 0; layer < 4; layer++) {
            const bool cross = ((layer + 1) % 2) == 0;
            for (int c = 0; c < nac; c++) {
                const long tok0 = (long)c * rA;
                __hip_bfloat16* Pc = Pb + tok0 * 768;
                rmsB(Pc, attn_n1 + layer * 768, bufA, 768, 768, 768, Mr);
                if (!cross) {
                    gemm(bufA, WqkvT + (long)layer * 2304 * 768, nullptr, bufQKV, 2304,
                         Mr, 2304, 2304, 768, FLAG_BF16, 0);
                } else {
                    if (nac != 1) cvt(actions + tok0 * 768, actB, rA * 768);
                    gemm(bufA, WqkvT + (long)layer * 2304 * 768, nullptr, bufQKV, 2304,
                         Mr, 768, 768, 768, FLAG_BF16, 0);
                    gemm(actB, WqkvT + (long)layer * 2304 * 768 + 768L * 768, nullptr,
                         bufQKV + 768, 2304, Mr, 1536, 1536, 768, FLAG_BF16, 0);
                }
                hipLaunchKernelGGL(attn_kernel, dim3(CB * 8), dim3(256), 0, stream,
                                   bufQKV, bufA);
                gemm(bufA, WoT + (long)layer * 589824, nullptr, Pc, 768,
                     Mr, 768, 768, 768, FLAG_ACC | FLAG_BF16, 0);
                rmsB(Pc, attn_n2 + layer * 768, bufA, 768, 768, 768, Mr);
                gemm(bufA, W1T + (long)layer * 2359296, ffn_b1 + layer * 3072, bufH, 3072,
                     Mr, 3072, 3072, 768, FLAG_GELU | FLAG_BF16, 0);
                gemm(bufH, W2T + (long)layer * 2359296, ffn_b2 + layer * 768, Pc, 768,
                     Mr, 768, 768, 3072, FLAG_ACC | FLAG_BF16, 0);
            }
        }
    }

    // ---- transpose to SSM layout (bf16 -> bf16) ----
    hipLaunchKernelGGL(transpose_kernel, dim3((int)((HALF / 4 + 255) / 256)), dim3(256), 0, stream, Pb, Zb);

    // ---- mamba blocks (bf16 residual in Zb) ----
    {
        const long rM = (long)CBT * 128;
        __hip_bfloat16* xn  = (__hip_bfloat16*)pbase;            // rM x 768
        __hip_bfloat16* zx  = xn + rM * 768;                     // rM x 3328
        float*          dtf = (float*)(zx + rM * 3328);          // rM x 24
        __hip_bfloat16* xc  = (__hip_bfloat16*)(dtf + rM * 24);  // rM x 1664
        __hip_bfloat16* yb  = xc + rM * 1664;                    // rM x 1536
        __hip_bfloat16* bcB = yb + rM * 1536;                    // rM x 128
        const int nmc = 256 / CBT;
        const int Mr = (int)rM;
        for (int m = 0; m < 4; m++) {
            for (int c = 0; c < nmc; c++) {
                __hip_bfloat16* Zc = Zb + (long)c * rM * 768;
                rmsB(Zc, ssm_norm + m * 768, xn, 768, 768, 768, Mr);
                gemm(xn, inT + (long)m * 3328 * 768, nullptr, zx, 3328,
                     Mr, 3224, 3328, 768, FLAG_BF16, 0);
                hipLaunchKernelGGL(conv_kernel, dim3((int)rM), dim3(256), 0, stream,
                                   zx, conv_w + m * 4 * 1664, conv_b + m * 1664, xc, bcB, rM);
                const long dtn = rM * 24;
                hipLaunchKernelGGL(dt_kernel, dim3((int)((dtn + 255) / 256)), dim3(256), 0, stream,
                                   zx, dt_bias + m * 24, dtf, dtn);
                hipLaunchKernelGGL(ssd_kernel, dim3(CBT * 24), dim3(256), 0, stream,
                                   zx, dtf, bcB, xc, A_log + m * 24, D_skip + m * 24,
                                   (m == 3) ? hout : nullptr, c * CBT);
                rmsB(xc, mamba_nw + m * 1536, yb, 1536, 1664, 1536, Mr);
                gemm(yb, outT + (long)m * 768 * 1536, nullptr, Zc, 768,
                     Mr, 768, 768, 1536, FLAG_ACC | FLAG_BF16, 0);
            }
        }
    }

    // ---- final projection: read Zb directly, permuted f32 epilogue ----
    gemm(Zb, projT, proj_b, out, 768, 32768, 768, 768, 768, FLAG_PERM, 0);
}